// Round 1
// 456.597 us; speedup vs baseline: 1.1923x; 1.1923x over previous
//
#include <hip/hip_runtime.h>

#define N_NODES 100000
#define N_EDGES 3200000
#define DIM 128

#define NB 391        // ceil(100000/256) buckets of 256 nodes
#define GCAP 9216     // per-bucket capacity; mean 8192, sigma ~90 (11 sigma)
#define PCHUNK 4096   // edges per partition block (782 blocks)

typedef __attribute__((ext_vector_type(8))) short bf16x8;   // 8 bf16 = 4 VGPRs
typedef __attribute__((ext_vector_type(4))) float f32x4;    // MFMA acc

// ---------------------------------------------------------------------------
// helpers
// ---------------------------------------------------------------------------
__device__ __forceinline__ unsigned short f2bf(float x) {
    unsigned u = __float_as_uint(x);
    unsigned r = (u + 0x7FFF + ((u >> 16) & 1)) >> 16;  // round-nearest-even
    return (unsigned short)r;
}

// async global->LDS, 16B per lane (dest must be linear: base + lane*16)
__device__ __forceinline__ void gld_lds16(const unsigned short* src, unsigned short* dst) {
    __builtin_amdgcn_global_load_lds(
        (const __attribute__((address_space(1))) unsigned int*)src,
        (__attribute__((address_space(3))) unsigned int*)dst, 16, 0, 0);
}

// ---------------------------------------------------------------------------
// K0: dual partition (dst-buckets for CSR + src-buckets for out-degree) with
// per-block range reservation. NO per-edge global atomics.
// ---------------------------------------------------------------------------
__global__ __launch_bounds__(256) void partition_kernel(const int* __restrict__ src,
                                                        const int* __restrict__ dst,
                                                        int* __restrict__ gcnt_d,
                                                        int* __restrict__ gcnt_s,
                                                        unsigned* __restrict__ bstore_d,
                                                        unsigned* __restrict__ bstore_s) {
    __shared__ int hist_d[NB], hofs_d[NB], cur_d[NB];
    __shared__ int hist_s[NB], hofs_s[NB], cur_s[NB];
    int t = threadIdx.x;
    for (int b = t; b < NB; b += 256) {
        hist_d[b] = 0; cur_d[b] = 0;
        hist_s[b] = 0; cur_s[b] = 0;
    }
    __syncthreads();
    int e0 = blockIdx.x * PCHUNK;
    int n = min(PCHUNK, N_EDGES - e0);
    for (int i = t; i < n; i += 256) {
        int s = src[e0 + i];
        int d = dst[e0 + i];
        atomicAdd(&hist_d[d >> 8], 1);
        atomicAdd(&hist_s[s >> 8], 1);
    }
    __syncthreads();
    for (int b = t; b < NB; b += 256) {
        hofs_d[b] = (hist_d[b] > 0) ? atomicAdd(&gcnt_d[b], hist_d[b]) : 0;
        hofs_s[b] = (hist_s[b] > 0) ? atomicAdd(&gcnt_s[b], hist_s[b]) : 0;
    }
    __syncthreads();
    for (int i = t; i < n; i += 256) {
        int s = src[e0 + i];   // L2-hit re-read
        int d = dst[e0 + i];
        int bd = d >> 8;
        int pd = hofs_d[bd] + atomicAdd(&cur_d[bd], 1);
        if (pd < GCAP)
            bstore_d[(size_t)bd * GCAP + pd] = ((unsigned)(d & 255) << 24) | (unsigned)s;
        int bs = s >> 8;
        int ps = hofs_s[bs] + atomicAdd(&cur_s[bs], 1);
        if (ps < GCAP)
            bstore_s[(size_t)bs * GCAP + ps] = (unsigned)(s & 255);
    }
}

// ---------------------------------------------------------------------------
// K1: scan of per-bucket dst totals -> bucket_base[0..NB]; also row_start[N].
// ---------------------------------------------------------------------------
__global__ void scanb_kernel(const int* __restrict__ gcnt_d, int* __restrict__ bucket_base,
                             int* __restrict__ row_start) {
    __shared__ int v[512];
    int t = threadIdx.x;
    v[t] = (t < NB) ? min(gcnt_d[t], GCAP) : 0;
    __syncthreads();
    for (int off = 1; off < 512; off <<= 1) {
        int x = (t >= off) ? v[t - off] : 0;
        __syncthreads();
        v[t] += x;
        __syncthreads();
    }
    if (t < NB) bucket_base[t + 1] = v[t];
    if (t == 0) {
        bucket_base[0] = 0;
        row_start[N_NODES] = v[NB - 1];
    }
}

// ---------------------------------------------------------------------------
// K2: out-degree histogram per src-bucket -> rn_out (no global atomics).
// ---------------------------------------------------------------------------
__global__ __launch_bounds__(256) void count_kernel(const int* __restrict__ gcnt_s,
                                                    const unsigned* __restrict__ bstore_s,
                                                    float* __restrict__ rn_out) {
    __shared__ int lcnt[256];
    int b = blockIdx.x;
    int t = threadIdx.x;
    lcnt[t] = 0;
    __syncthreads();
    int cnt = min(gcnt_s[b], GCAP);
    const unsigned* bs = &bstore_s[(size_t)b * GCAP];
    for (int i = t; i < cnt; i += 256)
        atomicAdd(&lcnt[bs[i] & 255], 1);
    __syncthreads();
    int node = b * 256 + t;
    if (node < N_NODES)
        rn_out[node] = rsqrtf((float)max(lcnt[t], 1));
}

// ---------------------------------------------------------------------------
// K3: per-bucket CSR fill + rn_in + row_start (no global atomics).
// ---------------------------------------------------------------------------
__global__ __launch_bounds__(256) void fill2_kernel(const int* __restrict__ gcnt_d,
                                                    const unsigned* __restrict__ bstore_d,
                                                    const int* __restrict__ bucket_base,
                                                    int* __restrict__ col,
                                                    int* __restrict__ row_start,
                                                    float* __restrict__ rn_in) {
    __shared__ int lcnt[256];
    __shared__ int lpre[256];
    __shared__ int lcur[256];
    __shared__ int stage[GCAP];
    int b = blockIdx.x;
    int t = threadIdx.x;
    int node0 = b * 256;
    int nn = min(256, N_NODES - node0);
    lcnt[t] = 0;
    __syncthreads();
    int cnt = min(gcnt_d[b], GCAP);
    int base = bucket_base[b];
    const unsigned* bs = &bstore_d[(size_t)b * GCAP];
    for (int i = t; i < cnt; i += 256)
        atomicAdd(&lcnt[bs[i] >> 24], 1);
    __syncthreads();
    int myc = lcnt[t];
    lpre[t] = myc;
    __syncthreads();
    for (int off = 1; off < 256; off <<= 1) {
        int x = (t >= off) ? lpre[t - off] : 0;
        __syncthreads();
        lpre[t] += x;
        __syncthreads();
    }
    int excl = lpre[t] - myc;
    if (t < nn) {
        row_start[node0 + t] = base + excl;
        rn_in[node0 + t] = rsqrtf((float)max(myc, 1));
    }
    lcur[t] = excl;
    __syncthreads();
    for (int i = t; i < cnt; i += 256) {
        unsigned e = bs[i];
        int p = atomicAdd(&lcur[e >> 24], 1);
        stage[p] = (int)(e & 0xFFFFFF);
    }
    __syncthreads();
    for (int i = t; i < cnt; i += 256)
        col[base + i] = stage[i];
}

// ---------------------------------------------------------------------------
// K4a: pack weights as transposed bf16 W_t[n][k].
// ---------------------------------------------------------------------------
__global__ void packw_kernel(const float* __restrict__ W_h, const float* __restrict__ W_hf,
                             unsigned short* __restrict__ W1_t,
                             unsigned short* __restrict__ W23_t,
                             unsigned short* __restrict__ Wf_t) {
    int idx = blockIdx.x * 256 + threadIdx.x;
    if (idx < 16384) {
        int n = idx >> 7, k = idx & 127;
        W1_t[idx] = f2bf(W_h[k * 384 + n]);
    } else if (idx < 49152) {
        int j = idx - 16384;
        int n = j >> 7, k = j & 127;
        W23_t[j] = f2bf(W_h[k * 384 + 128 + n]);
    } else if (idx < 81920) {
        int j = idx - 49152;
        int n = j >> 7, k = j & 127;
        Wf_t[j] = f2bf(W_hf[k * 256 + n]);
    }
}

// ---------------------------------------------------------------------------
// K4b: hidden f32 -> bf16
// ---------------------------------------------------------------------------
__global__ __launch_bounds__(256) void packh_kernel(const float* __restrict__ hidden,
                                                    unsigned short* __restrict__ hidden_bf) {
    int i = (blockIdx.x * 256 + threadIdx.x) * 8;   // grid covers exactly N*128
    float4 a = *reinterpret_cast<const float4*>(&hidden[i]);
    float4 b = *reinterpret_cast<const float4*>(&hidden[i + 4]);
    ushort4 lo, hi;
    lo.x = f2bf(a.x); lo.y = f2bf(a.y); lo.z = f2bf(a.z); lo.w = f2bf(a.w);
    hi.x = f2bf(b.x); hi.y = f2bf(b.y); hi.z = f2bf(b.z); hi.w = f2bf(b.w);
    *reinterpret_cast<ushort4*>(&hidden_bf[i]) = lo;
    *reinterpret_cast<ushort4*>(&hidden_bf[i + 4]) = hi;
}

// ---------------------------------------------------------------------------
// K5: GEMM1 via MFMA — h1n = bf16( (hidden @ W_h[:,0:128]) * rn_out ).
// v2: A-frags loaded DIRECTLY from global (each wave owns its 16 rows —
// the old LDS round-trip for A bought nothing). All of W1_t (32 KB) staged
// once into LDS via global_load_lds, shared by all 4 waves, XOR-swizzled at
// 16B granularity (kseg ^= row&7; linear DMA dest + inverse-swizzled global
// source + swizzled ds_read -> uniform bank distribution).
// ---------------------------------------------------------------------------
__global__ __launch_bounds__(256) void gemm1_mfma(const unsigned short* __restrict__ hidden_bf,
                                                  const unsigned short* __restrict__ W1_t,
                                                  const float* __restrict__ rn_out,
                                                  unsigned short* __restrict__ h1n) {
    __shared__ __align__(16) unsigned short Bs[16384];   // 32 KB: [128 n-rows][16 granules]
    int t = threadIdx.x;
    int row0 = blockIdx.x * 64;
    int lane = t & 63;
    int wave = t >> 6;
    int wr0 = wave * 16;
    int m = lane & 15;
    int q = lane >> 4;

    // A-frags direct from global (row clamped; OOB rows' results are never stored)
    int arow = min(row0 + wr0 + m, N_NODES - 1);
    bf16x8 af[4];
#pragma unroll
    for (int kc = 0; kc < 4; ++kc)
        af[kc] = *reinterpret_cast<const bf16x8*>(&hidden_bf[arow * 128 + kc * 32 + q * 8]);
    float s4[4];
#pragma unroll
    for (int reg = 0; reg < 4; ++reg) {
        int row = row0 + wr0 + q * 4 + reg;
        s4[reg] = (row < N_NODES) ? rn_out[row] : 0.f;
    }

    // stage all of W1_t, swizzled: LDS granule (row, kseg) holds logical (row, kseg^(row&7))
#pragma unroll
    for (int i = 0; i < 8; ++i) {
        int G = i * 256 + t;            // granule 0..2047
        int row = G >> 4;
        int kseg = G & 15;
        gld_lds16(&W1_t[row * 128 + ((kseg ^ (row & 7)) * 8)], &Bs[G * 8]);
    }
    __syncthreads();   // barrier drains vmcnt -> staged B visible

    f32x4 accn[8];
#pragma unroll
    for (int nt = 0; nt < 8; ++nt) {
        f32x4 acc = {0.f, 0.f, 0.f, 0.f};
#pragma unroll
        for (int kc = 0; kc < 4; ++kc) {
            int g = (nt * 16 + m) * 16 + ((kc * 4 + q) ^ (m & 7));
            bf16x8 b = *reinterpret_cast<const bf16x8*>(&Bs[g * 8]);
            acc = __builtin_amdgcn_mfma_f32_16x16x32_bf16(af[kc], b, acc, 0, 0, 0);
        }
        accn[nt] = acc;
    }
    __syncthreads();   // all waves done reading Bs; reuse as bf16 output stage

    unsigned short (*Sg)[136] = reinterpret_cast<unsigned short (*)[136]>(&Bs[0]);  // 17408 B
#pragma unroll
    for (int nt = 0; nt < 8; ++nt)
#pragma unroll
        for (int reg = 0; reg < 4; ++reg)
            Sg[wr0 + q * 4 + reg][nt * 16 + m] = f2bf(accn[nt][reg] * s4[reg]);
    __syncthreads();
    // coalesced stream-out: 8 bf16 (int4) per access
    int seg = (t & 15) * 8;
    int rb = t >> 4;            // 0..15
#pragma unroll
    for (int i = 0; i < 4; ++i) {
        int r = rb + i * 16;
        int row = row0 + r;
        if (row < N_NODES)
            *reinterpret_cast<int4*>(&h1n[row * 128 + seg]) =
                *reinterpret_cast<const int4*>(&Sg[r][seg]);
    }
}

// ---------------------------------------------------------------------------
// K6: pull aggregation — one wave per dst node; writes conv as packed bf16.
// ---------------------------------------------------------------------------
__global__ __launch_bounds__(256) void aggregate_kernel(const unsigned* __restrict__ h1n,
                                                        const int* __restrict__ row_start,
                                                        const int* __restrict__ col,
                                                        const float* __restrict__ rn_in,
                                                        unsigned* __restrict__ conv_bf) {
    int wave = threadIdx.x >> 6;
    int lane = threadIdx.x & 63;
    int node = blockIdx.x * 4 + wave;
    if (node >= N_NODES) return;
    int start = row_start[node];
    int end = row_start[node + 1];
    float2 acc = make_float2(0.f, 0.f);
    for (int j = start; j < end; j += 64) {
        int cnt = min(64, end - j);
        int myc = (lane < cnt) ? col[j + lane] : 0;
        int i = 0;
        for (; i + 4 <= cnt; i += 4) {
            int s0 = __shfl(myc, i);
            int s1 = __shfl(myc, i + 1);
            int s2 = __shfl(myc, i + 2);
            int s3 = __shfl(myc, i + 3);
            unsigned u0 = h1n[s0 * 64 + lane];
            unsigned u1 = h1n[s1 * 64 + lane];
            unsigned u2 = h1n[s2 * 64 + lane];
            unsigned u3 = h1n[s3 * 64 + lane];
            acc.x += __uint_as_float(u0 << 16) + __uint_as_float(u1 << 16) +
                     __uint_as_float(u2 << 16) + __uint_as_float(u3 << 16);
            acc.y += __uint_as_float(u0 & 0xFFFF0000u) + __uint_as_float(u1 & 0xFFFF0000u) +
                     __uint_as_float(u2 & 0xFFFF0000u) + __uint_as_float(u3 & 0xFFFF0000u);
        }
        for (; i < cnt; ++i) {
            int s = __shfl(myc, i);
            unsigned u = h1n[s * 64 + lane];
            acc.x += __uint_as_float(u << 16);
            acc.y += __uint_as_float(u & 0xFFFF0000u);
        }
    }
    float rn = rn_in[node];
    unsigned packed = ((unsigned)f2bf(acc.y * rn) << 16) | (unsigned)f2bf(acc.x * rn);
    conv_bf[node * 64 + lane] = packed;
}

// ---------------------------------------------------------------------------
// K7: fused final via MFMA. v2: A-frags (hidden + conv) direct from global;
// B (4 weight tiles per nt: W23[nt], W23[nt+8], Wf[nt], Wf[nt+8]) staged in
// LDS per nt, DOUBLE-BUFFERED with global_load_lds so L2 latency hides under
// the previous tile's 16 MFMAs. Same 16B-granule XOR swizzle as K5. Output
// stored directly (4x64B segments per store instr; no LDS out-stage) ->
// LDS = 32 KB -> 5 blocks/CU.
// ---------------------------------------------------------------------------
__global__ __launch_bounds__(256) void final_mfma(const unsigned short* __restrict__ hidden_bf,
                                                  const unsigned short* __restrict__ conv_bf,
                                                  const unsigned short* __restrict__ W23_t,
                                                  const unsigned short* __restrict__ Wf_t,
                                                  float* __restrict__ out) {
    __shared__ __align__(16) unsigned short Bst[2][8192];   // 2 x 16 KB (4 tiles x 16 x 128)
    int t = threadIdx.x;
    int row0 = blockIdx.x * 64;
    int lane = t & 63;
    int wave = t >> 6;
    int wr0 = wave * 16;
    int m = lane & 15;
    int q = lane >> 4;

    // A-frags direct from global (clamped row; OOB rows never stored)
    int arow = min(row0 + wr0 + m, N_NODES - 1);
    bf16x8 ah[4], ac[4];
#pragma unroll
    for (int kc = 0; kc < 4; ++kc) {
        int o = arow * 128 + kc * 32 + q * 8;
        ah[kc] = *reinterpret_cast<const bf16x8*>(&hidden_bf[o]);
        ac[kc] = *reinterpret_cast<const bf16x8*>(&conv_bf[o]);
    }

    // stage the 4 weight tiles for column-slice nt into buf (16 KB):
    // granule G = mat*256 + rowin*16 + kseg; content = logical kseg^(rowin&7)
    auto stage = [&](int nt, int buf) {
#pragma unroll
        for (int i = 0; i < 4; ++i) {           // mat = i (0:W23 nt, 1:W23 nt+8, 2:Wf nt, 3:Wf nt+8)
            int rowin = t >> 4;                 // 0..15
            int kseg = t & 15;
            int srow = ((i & 1) ? (nt + 8) : nt) * 16 + rowin;
            const unsigned short* Wp = (i < 2) ? W23_t : Wf_t;
            gld_lds16(&Wp[srow * 128 + ((kseg ^ (rowin & 7)) * 8)],
                      &Bst[buf][(i * 256 + t) * 8]);
        }
    };

    stage(0, 0);
    __syncthreads();   // drains vmcnt -> buf0 ready

#pragma unroll
    for (int nt = 0; nt < 8; ++nt) {
        if (nt < 7) stage(nt + 1, (nt + 1) & 1);     // prefetch next tile into other buffer
        const unsigned short* Bb = Bst[nt & 1];
        f32x4 h2 = {0.f, 0.f, 0.f, 0.f}, h3 = {0.f, 0.f, 0.f, 0.f};
        f32x4 f1 = {0.f, 0.f, 0.f, 0.f}, f2 = {0.f, 0.f, 0.f, 0.f};
#pragma unroll
        for (int kc = 0; kc < 4; ++kc) {
            int ks = (kc * 4 + q) ^ (m & 7);
            bf16x8 b2  = *reinterpret_cast<const bf16x8*>(&Bb[(0 * 256 + m * 16 + ks) * 8]);
            bf16x8 b3  = *reinterpret_cast<const bf16x8*>(&Bb[(1 * 256 + m * 16 + ks) * 8]);
            bf16x8 bf1 = *reinterpret_cast<const bf16x8*>(&Bb[(2 * 256 + m * 16 + ks) * 8]);
            bf16x8 bf2 = *reinterpret_cast<const bf16x8*>(&Bb[(3 * 256 + m * 16 + ks) * 8]);
            h2 = __builtin_amdgcn_mfma_f32_16x16x32_bf16(ah[kc], b2, h2, 0, 0, 0);
            h3 = __builtin_amdgcn_mfma_f32_16x16x32_bf16(ah[kc], b3, h3, 0, 0, 0);
            f1 = __builtin_amdgcn_mfma_f32_16x16x32_bf16(ac[kc], bf1, f1, 0, 0, 0);
            f2 = __builtin_amdgcn_mfma_f32_16x16x32_bf16(ac[kc], bf2, f2, 0, 0, 0);
        }
        int colb = nt * 16 + m;
#pragma unroll
        for (int reg = 0; reg < 4; ++reg) {
            int row = row0 + wr0 + q * 4 + reg;
            float g = fmaxf(f1[reg] + h2[reg], 0.f);
            float o = h3[reg] + g * f2[reg];
            if (row < N_NODES) {
                out[(size_t)row * 128 + colb] = o;
                out[(size_t)(N_NODES + row) * 128 + colb] = o;
            }
        }
        __syncthreads();   // all waves done with buf[nt&1]; prefetch drained for next iter
    }
}

// ---------------------------------------------------------------------------
// launch
// ---------------------------------------------------------------------------
extern "C" void kernel_launch(void* const* d_in, const int* in_sizes, int n_in,
                              void* d_out, int out_size, void* d_ws, size_t ws_size,
                              hipStream_t stream) {
    const float* hidden = (const float*)d_in[0];
    const int* src = (const int*)d_in[1];
    const int* dst = (const int*)d_in[2];
    const float* W_h = (const float*)d_in[3];
    const float* W_hf = (const float*)d_in[4];
    float* out = (float*)d_out;

    auto align_up = [](size_t x) { return (x + 255) & ~(size_t)255; };
    char* p = (char*)d_ws;
    size_t off = 0;
    unsigned short* h1n = (unsigned short*)(p + off); off += align_up((size_t)N_NODES * 128 * 2);
    unsigned short* conv_bf = (unsigned short*)(p + off); off += align_up((size_t)N_NODES * 128 * 2);
    unsigned short* hidden_bf = (unsigned short*)(p + off); off += align_up((size_t)N_NODES * 128 * 2);
    int* col = (int*)(p + off); off += align_up((size_t)N_EDGES * 4);
    unsigned* bstore_d = (unsigned*)(p + off); off += align_up((size_t)NB * GCAP * 4);
    unsigned* bstore_s = (unsigned*)(p + off); off += align_up((size_t)NB * GCAP * 4);
    int* gcnt_d = (int*)(p + off); off += align_up((size_t)NB * 4);
    int* gcnt_s = (int*)(p + off); off += align_up((size_t)NB * 4);
    int* bucket_base = (int*)(p + off); off += align_up((size_t)(NB + 1) * 4);
    int* row_start = (int*)(p + off); off += align_up((size_t)(N_NODES + 1) * 4);
    float* rn_out = (float*)(p + off); off += align_up((size_t)N_NODES * 4);
    float* rn_in = (float*)(p + off); off += align_up((size_t)N_NODES * 4);
    unsigned short* W1_t = (unsigned short*)(p + off); off += align_up((size_t)128 * 128 * 2);
    unsigned short* W23_t = (unsigned short*)(p + off); off += align_up((size_t)256 * 128 * 2);
    unsigned short* Wf_t = (unsigned short*)(p + off); off += align_up((size_t)256 * 128 * 2);

    (void)hipMemsetAsync(gcnt_d, 0, (size_t)NB * 4, stream);
    (void)hipMemsetAsync(gcnt_s, 0, (size_t)NB * 4, stream);

    partition_kernel<<<(N_EDGES + PCHUNK - 1) / PCHUNK, 256, 0, stream>>>(
        src, dst, gcnt_d, gcnt_s, bstore_d, bstore_s);
    scanb_kernel<<<1, 512, 0, stream>>>(gcnt_d, bucket_base, row_start);
    count_kernel<<<NB, 256, 0, stream>>>(gcnt_s, bstore_s, rn_out);
    fill2_kernel<<<NB, 256, 0, stream>>>(gcnt_d, bstore_d, bucket_base, col, row_start, rn_in);
    packw_kernel<<<(81920 + 255) / 256, 256, 0, stream>>>(W_h, W_hf, W1_t, W23_t, Wf_t);
    packh_kernel<<<(N_NODES * 128) / (256 * 8), 256, 0, stream>>>(hidden, hidden_bf);
    gemm1_mfma<<<(N_NODES + 63) / 64, 256, 0, stream>>>(hidden_bf, W1_t, rn_out, h1n);
    aggregate_kernel<<<(N_NODES + 3) / 4, 256, 0, stream>>>(
        (const unsigned*)h1n, row_start, col, rn_in, (unsigned*)conv_bf);
    final_mfma<<<(N_NODES + 63) / 64, 256, 0, stream>>>(hidden_bf, conv_bf, W23_t, Wf_t, out);
}

// Round 2
// 451.754 us; speedup vs baseline: 1.2050x; 1.0107x over previous
//
#include <hip/hip_runtime.h>

#define N_NODES 100000
#define N_EDGES 3200000
#define DIM 128

#define NB 391        // ceil(100000/256) buckets of 256 nodes
#define GCAP 9216     // per-bucket capacity; mean 8192, sigma ~90 (11 sigma)
#define PCHUNK 4096   // edges per partition block (782 blocks)

typedef __attribute__((ext_vector_type(8))) short bf16x8;   // 8 bf16 = 4 VGPRs
typedef __attribute__((ext_vector_type(4))) float f32x4;    // MFMA acc

// ---------------------------------------------------------------------------
// helpers
// ---------------------------------------------------------------------------
__device__ __forceinline__ unsigned short f2bf(float x) {
    unsigned u = __float_as_uint(x);
    unsigned r = (u + 0x7FFF + ((u >> 16) & 1)) >> 16;  // round-nearest-even
    return (unsigned short)r;
}

// async global->LDS, 16B per lane (dest must be linear: base + lane*16)
__device__ __forceinline__ void gld_lds16(const unsigned short* src, unsigned short* dst) {
    __builtin_amdgcn_global_load_lds(
        (const __attribute__((address_space(1))) unsigned int*)src,
        (__attribute__((address_space(3))) unsigned int*)dst, 16, 0, 0);
}

// ---------------------------------------------------------------------------
// K0: dual partition (dst-buckets for CSR + src-buckets for out-degree) with
// per-block range reservation. NO per-edge global atomics.
// ---------------------------------------------------------------------------
__global__ __launch_bounds__(256) void partition_kernel(const int* __restrict__ src,
                                                        const int* __restrict__ dst,
                                                        int* __restrict__ gcnt_d,
                                                        int* __restrict__ gcnt_s,
                                                        unsigned* __restrict__ bstore_d,
                                                        unsigned* __restrict__ bstore_s) {
    __shared__ int hist_d[NB], hofs_d[NB], cur_d[NB];
    __shared__ int hist_s[NB], hofs_s[NB], cur_s[NB];
    int t = threadIdx.x;
    for (int b = t; b < NB; b += 256) {
        hist_d[b] = 0; cur_d[b] = 0;
        hist_s[b] = 0; cur_s[b] = 0;
    }
    __syncthreads();
    int e0 = blockIdx.x * PCHUNK;
    int n = min(PCHUNK, N_EDGES - e0);
    for (int i = t; i < n; i += 256) {
        int s = src[e0 + i];
        int d = dst[e0 + i];
        atomicAdd(&hist_d[d >> 8], 1);
        atomicAdd(&hist_s[s >> 8], 1);
    }
    __syncthreads();
    for (int b = t; b < NB; b += 256) {
        hofs_d[b] = (hist_d[b] > 0) ? atomicAdd(&gcnt_d[b], hist_d[b]) : 0;
        hofs_s[b] = (hist_s[b] > 0) ? atomicAdd(&gcnt_s[b], hist_s[b]) : 0;
    }
    __syncthreads();
    for (int i = t; i < n; i += 256) {
        int s = src[e0 + i];   // L2-hit re-read
        int d = dst[e0 + i];
        int bd = d >> 8;
        int pd = hofs_d[bd] + atomicAdd(&cur_d[bd], 1);
        if (pd < GCAP)
            bstore_d[(size_t)bd * GCAP + pd] = ((unsigned)(d & 255) << 24) | (unsigned)s;
        int bs = s >> 8;
        int ps = hofs_s[bs] + atomicAdd(&cur_s[bs], 1);
        if (ps < GCAP)
            bstore_s[(size_t)bs * GCAP + ps] = (unsigned)(s & 255);
    }
}

// ---------------------------------------------------------------------------
// K1: scan of per-bucket dst totals -> bucket_base[0..NB]; also row_start[N].
// ---------------------------------------------------------------------------
__global__ void scanb_kernel(const int* __restrict__ gcnt_d, int* __restrict__ bucket_base,
                             int* __restrict__ row_start) {
    __shared__ int v[512];
    int t = threadIdx.x;
    v[t] = (t < NB) ? min(gcnt_d[t], GCAP) : 0;
    __syncthreads();
    for (int off = 1; off < 512; off <<= 1) {
        int x = (t >= off) ? v[t - off] : 0;
        __syncthreads();
        v[t] += x;
        __syncthreads();
    }
    if (t < NB) bucket_base[t + 1] = v[t];
    if (t == 0) {
        bucket_base[0] = 0;
        row_start[N_NODES] = v[NB - 1];
    }
}

// ---------------------------------------------------------------------------
// K2: out-degree histogram per src-bucket -> rn_out (no global atomics).
// ---------------------------------------------------------------------------
__global__ __launch_bounds__(256) void count_kernel(const int* __restrict__ gcnt_s,
                                                    const unsigned* __restrict__ bstore_s,
                                                    float* __restrict__ rn_out) {
    __shared__ int lcnt[256];
    int b = blockIdx.x;
    int t = threadIdx.x;
    lcnt[t] = 0;
    __syncthreads();
    int cnt = min(gcnt_s[b], GCAP);
    const unsigned* bs = &bstore_s[(size_t)b * GCAP];
    for (int i = t; i < cnt; i += 256)
        atomicAdd(&lcnt[bs[i] & 255], 1);
    __syncthreads();
    int node = b * 256 + t;
    if (node < N_NODES)
        rn_out[node] = rsqrtf((float)max(lcnt[t], 1));
}

// ---------------------------------------------------------------------------
// K3: per-bucket CSR fill + rn_in + row_start (no global atomics).
// ---------------------------------------------------------------------------
__global__ __launch_bounds__(256) void fill2_kernel(const int* __restrict__ gcnt_d,
                                                    const unsigned* __restrict__ bstore_d,
                                                    const int* __restrict__ bucket_base,
                                                    int* __restrict__ col,
                                                    int* __restrict__ row_start,
                                                    float* __restrict__ rn_in) {
    __shared__ int lcnt[256];
    __shared__ int lpre[256];
    __shared__ int lcur[256];
    __shared__ int stage[GCAP];
    int b = blockIdx.x;
    int t = threadIdx.x;
    int node0 = b * 256;
    int nn = min(256, N_NODES - node0);
    lcnt[t] = 0;
    __syncthreads();
    int cnt = min(gcnt_d[b], GCAP);
    int base = bucket_base[b];
    const unsigned* bs = &bstore_d[(size_t)b * GCAP];
    for (int i = t; i < cnt; i += 256)
        atomicAdd(&lcnt[bs[i] >> 24], 1);
    __syncthreads();
    int myc = lcnt[t];
    lpre[t] = myc;
    __syncthreads();
    for (int off = 1; off < 256; off <<= 1) {
        int x = (t >= off) ? lpre[t - off] : 0;
        __syncthreads();
        lpre[t] += x;
        __syncthreads();
    }
    int excl = lpre[t] - myc;
    if (t < nn) {
        row_start[node0 + t] = base + excl;
        rn_in[node0 + t] = rsqrtf((float)max(myc, 1));
    }
    lcur[t] = excl;
    __syncthreads();
    for (int i = t; i < cnt; i += 256) {
        unsigned e = bs[i];
        int p = atomicAdd(&lcur[e >> 24], 1);
        stage[p] = (int)(e & 0xFFFFFF);
    }
    __syncthreads();
    for (int i = t; i < cnt; i += 256)
        col[base + i] = stage[i];
}

// ---------------------------------------------------------------------------
// K4a: pack weights as transposed bf16 W_t[n][k].
// ---------------------------------------------------------------------------
__global__ void packw_kernel(const float* __restrict__ W_h, const float* __restrict__ W_hf,
                             unsigned short* __restrict__ W1_t,
                             unsigned short* __restrict__ W23_t,
                             unsigned short* __restrict__ Wf_t) {
    int idx = blockIdx.x * 256 + threadIdx.x;
    if (idx < 16384) {
        int n = idx >> 7, k = idx & 127;
        W1_t[idx] = f2bf(W_h[k * 384 + n]);
    } else if (idx < 49152) {
        int j = idx - 16384;
        int n = j >> 7, k = j & 127;
        W23_t[j] = f2bf(W_h[k * 384 + 128 + n]);
    } else if (idx < 81920) {
        int j = idx - 49152;
        int n = j >> 7, k = j & 127;
        Wf_t[j] = f2bf(W_hf[k * 256 + n]);
    }
}

// ---------------------------------------------------------------------------
// K4b: hidden f32 -> bf16
// ---------------------------------------------------------------------------
__global__ __launch_bounds__(256) void packh_kernel(const float* __restrict__ hidden,
                                                    unsigned short* __restrict__ hidden_bf) {
    int i = (blockIdx.x * 256 + threadIdx.x) * 8;   // grid covers exactly N*128
    float4 a = *reinterpret_cast<const float4*>(&hidden[i]);
    float4 b = *reinterpret_cast<const float4*>(&hidden[i + 4]);
    ushort4 lo, hi;
    lo.x = f2bf(a.x); lo.y = f2bf(a.y); lo.z = f2bf(a.z); lo.w = f2bf(a.w);
    hi.x = f2bf(b.x); hi.y = f2bf(b.y); hi.z = f2bf(b.z); hi.w = f2bf(b.w);
    *reinterpret_cast<ushort4*>(&hidden_bf[i]) = lo;
    *reinterpret_cast<ushort4*>(&hidden_bf[i + 4]) = hi;
}

// ---------------------------------------------------------------------------
// K5: GEMM1 via MFMA — h1n = bf16( (hidden @ W_h[:,0:128]) * rn_out ).
// A-frags direct from global; all of W1_t (32 KB) staged once into LDS via
// global_load_lds, shared by all 4 waves, XOR-swizzled at 16B granularity.
// ---------------------------------------------------------------------------
__global__ __launch_bounds__(256) void gemm1_mfma(const unsigned short* __restrict__ hidden_bf,
                                                  const unsigned short* __restrict__ W1_t,
                                                  const float* __restrict__ rn_out,
                                                  unsigned short* __restrict__ h1n) {
    __shared__ __align__(16) unsigned short Bs[16384];   // 32 KB: [128 n-rows][16 granules]
    int t = threadIdx.x;
    int row0 = blockIdx.x * 64;
    int lane = t & 63;
    int wave = t >> 6;
    int wr0 = wave * 16;
    int m = lane & 15;
    int q = lane >> 4;

    // A-frags direct from global (row clamped; OOB rows' results are never stored)
    int arow = min(row0 + wr0 + m, N_NODES - 1);
    bf16x8 af[4];
#pragma unroll
    for (int kc = 0; kc < 4; ++kc)
        af[kc] = *reinterpret_cast<const bf16x8*>(&hidden_bf[arow * 128 + kc * 32 + q * 8]);
    float s4[4];
#pragma unroll
    for (int reg = 0; reg < 4; ++reg) {
        int row = row0 + wr0 + q * 4 + reg;
        s4[reg] = (row < N_NODES) ? rn_out[row] : 0.f;
    }

    // stage all of W1_t, swizzled: LDS granule (row, kseg) holds logical (row, kseg^(row&7))
#pragma unroll
    for (int i = 0; i < 8; ++i) {
        int G = i * 256 + t;            // granule 0..2047
        int row = G >> 4;
        int kseg = G & 15;
        gld_lds16(&W1_t[row * 128 + ((kseg ^ (row & 7)) * 8)], &Bs[G * 8]);
    }
    __syncthreads();   // barrier drains vmcnt -> staged B visible

    f32x4 accn[8];
#pragma unroll
    for (int nt = 0; nt < 8; ++nt) {
        f32x4 acc = {0.f, 0.f, 0.f, 0.f};
#pragma unroll
        for (int kc = 0; kc < 4; ++kc) {
            int g = (nt * 16 + m) * 16 + ((kc * 4 + q) ^ (m & 7));
            bf16x8 b = *reinterpret_cast<const bf16x8*>(&Bs[g * 8]);
            acc = __builtin_amdgcn_mfma_f32_16x16x32_bf16(af[kc], b, acc, 0, 0, 0);
        }
        accn[nt] = acc;
    }
    __syncthreads();   // all waves done reading Bs; reuse as bf16 output stage

    unsigned short (*Sg)[136] = reinterpret_cast<unsigned short (*)[136]>(&Bs[0]);  // 17408 B
#pragma unroll
    for (int nt = 0; nt < 8; ++nt)
#pragma unroll
        for (int reg = 0; reg < 4; ++reg)
            Sg[wr0 + q * 4 + reg][nt * 16 + m] = f2bf(accn[nt][reg] * s4[reg]);
    __syncthreads();
    // coalesced stream-out: 8 bf16 (int4) per access
    int seg = (t & 15) * 8;
    int rb = t >> 4;            // 0..15
#pragma unroll
    for (int i = 0; i < 4; ++i) {
        int r = rb + i * 16;
        int row = row0 + r;
        if (row < N_NODES)
            *reinterpret_cast<int4*>(&h1n[row * 128 + seg]) =
                *reinterpret_cast<const int4*>(&Sg[r][seg]);
    }
}

// ---------------------------------------------------------------------------
// K6: pull aggregation — one wave per dst node; writes conv as packed bf16.
// v3: latency/ILP attack. (a) edge index broadcast via v_readlane (SGPR) ->
// row base folds into the scalar operand of global_load; per-lane voffset
// (lane*4) computed ONCE — no ds_bpermute, no per-edge VALU address math.
// (b) 16 loads in flight per wave (was 4). (c) split accumulators to halve
// the fadd dependency chain. VGPR ~48 -> still 8 waves/SIMD.
// ---------------------------------------------------------------------------
__global__ __launch_bounds__(256) void aggregate_kernel(const unsigned* __restrict__ h1n,
                                                        const int* __restrict__ row_start,
                                                        const int* __restrict__ col,
                                                        const float* __restrict__ rn_in,
                                                        unsigned* __restrict__ conv_bf) {
    int wave = threadIdx.x >> 6;
    int lane = threadIdx.x & 63;
    int node = blockIdx.x * 4 + wave;
    if (node >= N_NODES) return;
    int start = row_start[node];
    int end = row_start[node + 1];
    float ax0 = 0.f, ax1 = 0.f, ay0 = 0.f, ay1 = 0.f;
    for (int j = start; j < end; j += 64) {
        int cnt = min(64, end - j);
        int myc = (lane < cnt) ? col[j + lane] : 0;
        int i = 0;
        for (; i + 16 <= cnt; i += 16) {
            unsigned u[16];
#pragma unroll
            for (int k = 0; k < 16; ++k) {
                int s = __builtin_amdgcn_readlane(myc, i + k);   // SGPR broadcast
                u[k] = h1n[s * 64 + lane];                       // saddr-form load
            }
#pragma unroll
            for (int k = 0; k < 16; k += 2) {
                ax0 += __uint_as_float(u[k] << 16);
                ay0 += __uint_as_float(u[k] & 0xFFFF0000u);
                ax1 += __uint_as_float(u[k + 1] << 16);
                ay1 += __uint_as_float(u[k + 1] & 0xFFFF0000u);
            }
        }
        for (; i + 4 <= cnt; i += 4) {
            unsigned u[4];
#pragma unroll
            for (int k = 0; k < 4; ++k) {
                int s = __builtin_amdgcn_readlane(myc, i + k);
                u[k] = h1n[s * 64 + lane];
            }
#pragma unroll
            for (int k = 0; k < 4; k += 2) {
                ax0 += __uint_as_float(u[k] << 16);
                ay0 += __uint_as_float(u[k] & 0xFFFF0000u);
                ax1 += __uint_as_float(u[k + 1] << 16);
                ay1 += __uint_as_float(u[k + 1] & 0xFFFF0000u);
            }
        }
        for (; i < cnt; ++i) {
            int s = __builtin_amdgcn_readlane(myc, i);
            unsigned u = h1n[s * 64 + lane];
            ax0 += __uint_as_float(u << 16);
            ay0 += __uint_as_float(u & 0xFFFF0000u);
        }
    }
    float rn = rn_in[node];
    float ax = ax0 + ax1, ay = ay0 + ay1;
    unsigned packed = ((unsigned)f2bf(ay * rn) << 16) | (unsigned)f2bf(ax * rn);
    conv_bf[node * 64 + lane] = packed;
}

// ---------------------------------------------------------------------------
// K7: fused final via MFMA. A-frags (hidden + conv) direct from global;
// B (4 weight tiles per nt) staged in LDS per nt, double-buffered with
// global_load_lds. 16B-granule XOR swizzle. Output stored directly.
// ---------------------------------------------------------------------------
__global__ __launch_bounds__(256) void final_mfma(const unsigned short* __restrict__ hidden_bf,
                                                  const unsigned short* __restrict__ conv_bf,
                                                  const unsigned short* __restrict__ W23_t,
                                                  const unsigned short* __restrict__ Wf_t,
                                                  float* __restrict__ out) {
    __shared__ __align__(16) unsigned short Bst[2][8192];   // 2 x 16 KB (4 tiles x 16 x 128)
    int t = threadIdx.x;
    int row0 = blockIdx.x * 64;
    int lane = t & 63;
    int wave = t >> 6;
    int wr0 = wave * 16;
    int m = lane & 15;
    int q = lane >> 4;

    // A-frags direct from global (clamped row; OOB rows never stored)
    int arow = min(row0 + wr0 + m, N_NODES - 1);
    bf16x8 ah[4], ac[4];
#pragma unroll
    for (int kc = 0; kc < 4; ++kc) {
        int o = arow * 128 + kc * 32 + q * 8;
        ah[kc] = *reinterpret_cast<const bf16x8*>(&hidden_bf[o]);
        ac[kc] = *reinterpret_cast<const bf16x8*>(&conv_bf[o]);
    }

    // stage the 4 weight tiles for column-slice nt into buf (16 KB):
    // granule G = mat*256 + rowin*16 + kseg; content = logical kseg^(rowin&7)
    auto stage = [&](int nt, int buf) {
#pragma unroll
        for (int i = 0; i < 4; ++i) {           // mat = i (0:W23 nt, 1:W23 nt+8, 2:Wf nt, 3:Wf nt+8)
            int rowin = t >> 4;                 // 0..15
            int kseg = t & 15;
            int srow = ((i & 1) ? (nt + 8) : nt) * 16 + rowin;
            const unsigned short* Wp = (i < 2) ? W23_t : Wf_t;
            gld_lds16(&Wp[srow * 128 + ((kseg ^ (rowin & 7)) * 8)],
                      &Bst[buf][(i * 256 + t) * 8]);
        }
    };

    stage(0, 0);
    __syncthreads();   // drains vmcnt -> buf0 ready

#pragma unroll
    for (int nt = 0; nt < 8; ++nt) {
        if (nt < 7) stage(nt + 1, (nt + 1) & 1);     // prefetch next tile into other buffer
        const unsigned short* Bb = Bst[nt & 1];
        f32x4 h2 = {0.f, 0.f, 0.f, 0.f}, h3 = {0.f, 0.f, 0.f, 0.f};
        f32x4 f1 = {0.f, 0.f, 0.f, 0.f}, f2 = {0.f, 0.f, 0.f, 0.f};
#pragma unroll
        for (int kc = 0; kc < 4; ++kc) {
            int ks = (kc * 4 + q) ^ (m & 7);
            bf16x8 b2  = *reinterpret_cast<const bf16x8*>(&Bb[(0 * 256 + m * 16 + ks) * 8]);
            bf16x8 b3  = *reinterpret_cast<const bf16x8*>(&Bb[(1 * 256 + m * 16 + ks) * 8]);
            bf16x8 bf1 = *reinterpret_cast<const bf16x8*>(&Bb[(2 * 256 + m * 16 + ks) * 8]);
            bf16x8 bf2 = *reinterpret_cast<const bf16x8*>(&Bb[(3 * 256 + m * 16 + ks) * 8]);
            h2 = __builtin_amdgcn_mfma_f32_16x16x32_bf16(ah[kc], b2, h2, 0, 0, 0);
            h3 = __builtin_amdgcn_mfma_f32_16x16x32_bf16(ah[kc], b3, h3, 0, 0, 0);
            f1 = __builtin_amdgcn_mfma_f32_16x16x32_bf16(ac[kc], bf1, f1, 0, 0, 0);
            f2 = __builtin_amdgcn_mfma_f32_16x16x32_bf16(ac[kc], bf2, f2, 0, 0, 0);
        }
        int colb = nt * 16 + m;
#pragma unroll
        for (int reg = 0; reg < 4; ++reg) {
            int row = row0 + wr0 + q * 4 + reg;
            float g = fmaxf(f1[reg] + h2[reg], 0.f);
            float o = h3[reg] + g * f2[reg];
            if (row < N_NODES) {
                out[(size_t)row * 128 + colb] = o;
                out[(size_t)(N_NODES + row) * 128 + colb] = o;
            }
        }
        __syncthreads();   // all waves done with buf[nt&1]; prefetch drained for next iter
    }
}

// ---------------------------------------------------------------------------
// launch
// ---------------------------------------------------------------------------
extern "C" void kernel_launch(void* const* d_in, const int* in_sizes, int n_in,
                              void* d_out, int out_size, void* d_ws, size_t ws_size,
                              hipStream_t stream) {
    const float* hidden = (const float*)d_in[0];
    const int* src = (const int*)d_in[1];
    const int* dst = (const int*)d_in[2];
    const float* W_h = (const float*)d_in[3];
    const float* W_hf = (const float*)d_in[4];
    float* out = (float*)d_out;

    auto align_up = [](size_t x) { return (x + 255) & ~(size_t)255; };
    char* p = (char*)d_ws;
    size_t off = 0;
    unsigned short* h1n = (unsigned short*)(p + off); off += align_up((size_t)N_NODES * 128 * 2);
    unsigned short* conv_bf = (unsigned short*)(p + off); off += align_up((size_t)N_NODES * 128 * 2);
    unsigned short* hidden_bf = (unsigned short*)(p + off); off += align_up((size_t)N_NODES * 128 * 2);
    int* col = (int*)(p + off); off += align_up((size_t)N_EDGES * 4);
    unsigned* bstore_d = (unsigned*)(p + off); off += align_up((size_t)NB * GCAP * 4);
    unsigned* bstore_s = (unsigned*)(p + off); off += align_up((size_t)NB * GCAP * 4);
    int* gcnt_d = (int*)(p + off); off += align_up((size_t)NB * 4);
    int* gcnt_s = (int*)(p + off); off += align_up((size_t)NB * 4);
    int* bucket_base = (int*)(p + off); off += align_up((size_t)(NB + 1) * 4);
    int* row_start = (int*)(p + off); off += align_up((size_t)(N_NODES + 1) * 4);
    float* rn_out = (float*)(p + off); off += align_up((size_t)N_NODES * 4);
    float* rn_in = (float*)(p + off); off += align_up((size_t)N_NODES * 4);
    unsigned short* W1_t = (unsigned short*)(p + off); off += align_up((size_t)128 * 128 * 2);
    unsigned short* W23_t = (unsigned short*)(p + off); off += align_up((size_t)256 * 128 * 2);
    unsigned short* Wf_t = (unsigned short*)(p + off); off += align_up((size_t)256 * 128 * 2);

    (void)hipMemsetAsync(gcnt_d, 0, (size_t)NB * 4, stream);
    (void)hipMemsetAsync(gcnt_s, 0, (size_t)NB * 4, stream);

    partition_kernel<<<(N_EDGES + PCHUNK - 1) / PCHUNK, 256, 0, stream>>>(
        src, dst, gcnt_d, gcnt_s, bstore_d, bstore_s);
    scanb_kernel<<<1, 512, 0, stream>>>(gcnt_d, bucket_base, row_start);
    count_kernel<<<NB, 256, 0, stream>>>(gcnt_s, bstore_s, rn_out);
    fill2_kernel<<<NB, 256, 0, stream>>>(gcnt_d, bstore_d, bucket_base, col, row_start, rn_in);
    packw_kernel<<<(81920 + 255) / 256, 256, 0, stream>>>(W_h, W_hf, W1_t, W23_t, Wf_t);
    packh_kernel<<<(N_NODES * 128) / (256 * 8), 256, 0, stream>>>(hidden, hidden_bf);
    gemm1_mfma<<<(N_NODES + 63) / 64, 256, 0, stream>>>(hidden_bf, W1_t, rn_out, h1n);
    aggregate_kernel<<<(N_NODES + 3) / 4, 256, 0, stream>>>(
        (const unsigned*)h1n, row_start, col, rn_in, (unsigned*)conv_bf);
    final_mfma<<<(N_NODES + 63) / 64, 256, 0, stream>>>(hidden_bf, conv_bf, W23_t, Wf_t, out);
}

// Round 4
// 418.956 us; speedup vs baseline: 1.2994x; 1.0783x over previous
//
#include <hip/hip_runtime.h>

#define N_NODES 100000
#define N_EDGES 3200000
#define DIM 128

#define NB 391        // ceil(100000/256) buckets of 256 nodes
#define GCAP 9216     // per-bucket capacity; mean 8192, sigma ~90 (11 sigma)
#define PCHUNK 4096   // edges per partition block (782 blocks)

typedef __attribute__((ext_vector_type(8))) short bf16x8;   // 8 bf16 = 4 VGPRs
typedef __attribute__((ext_vector_type(4))) float f32x4;    // MFMA acc

// ---------------------------------------------------------------------------
// helpers
// ---------------------------------------------------------------------------
__device__ __forceinline__ unsigned short f2bf(float x) {
    unsigned u = __float_as_uint(x);
    unsigned r = (u + 0x7FFF + ((u >> 16) & 1)) >> 16;  // round-nearest-even
    return (unsigned short)r;
}

// async global->LDS, 16B per lane (dest must be linear: base + lane*16)
__device__ __forceinline__ void gld_lds16(const unsigned short* src, unsigned short* dst) {
    __builtin_amdgcn_global_load_lds(
        (const __attribute__((address_space(1))) unsigned int*)src,
        (__attribute__((address_space(3))) unsigned int*)dst, 16, 0, 0);
}

// ---------------------------------------------------------------------------
// K0: dual partition (dst-buckets for CSR + src-buckets for out-degree).
// v4: stage-then-burst. Per-block LDS histogram -> block-local prefix scan ->
// scatter into bucket-GROUPED LDS stage -> single coalesced burst copy-out.
// Kills the 7x write amplification (trickled partial-line scatter across
// non-coherent XCD L2s) seen in v3. bstore_s is 1 byte/entry.
// (Resubmit of round-3 source: bench failed on container acquisition, not
// on the kernel; no counter evidence to revise against.)
// ---------------------------------------------------------------------------
__global__ __launch_bounds__(256) void partition_kernel(const int* __restrict__ src,
                                                        const int* __restrict__ dst,
                                                        int* __restrict__ gcnt_d,
                                                        int* __restrict__ gcnt_s,
                                                        unsigned* __restrict__ bstore_d,
                                                        unsigned char* __restrict__ bstore_s) {
    __shared__ int hist_d[NB], cur_d[NB], hofs_d[NB];
    __shared__ int hist_s[NB], cur_s[NB], hofs_s[NB];
    __shared__ int vsc_d[512], vsc_s[512];          // inclusive scans
    __shared__ unsigned stage_d[PCHUNK];            // bucket-grouped entries
    __shared__ unsigned short bmap_d[PCHUNK];       // slot -> bucket
    __shared__ unsigned char stage_s[PCHUNK];
    __shared__ unsigned short bmap_s[PCHUNK];
    int t = threadIdx.x;
    for (int b = t; b < NB; b += 256) { hist_d[b] = 0; hist_s[b] = 0; }
    __syncthreads();
    int e0 = blockIdx.x * PCHUNK;
    int n = min(PCHUNK, N_EDGES - e0);
    for (int i = t; i < n; i += 256) {
        int s = src[e0 + i];
        int d = dst[e0 + i];
        atomicAdd(&hist_d[d >> 8], 1);
        atomicAdd(&hist_s[s >> 8], 1);
    }
    __syncthreads();
    // global range reservation (unchanged semantics)
    for (int b = t; b < NB; b += 256) {
        hofs_d[b] = (hist_d[b] > 0) ? atomicAdd(&gcnt_d[b], hist_d[b]) : 0;
        hofs_s[b] = (hist_s[b] > 0) ? atomicAdd(&gcnt_s[b], hist_s[b]) : 0;
    }
    // block-local inclusive scan over NB buckets (512 slots, 2 per thread)
    vsc_d[t]       = (t < NB) ? hist_d[t] : 0;
    vsc_d[t + 256] = (t + 256 < NB) ? hist_d[t + 256] : 0;
    vsc_s[t]       = (t < NB) ? hist_s[t] : 0;
    vsc_s[t + 256] = (t + 256 < NB) ? hist_s[t + 256] : 0;
    __syncthreads();
    for (int off = 1; off < 512; off <<= 1) {
        int d0 = (t >= off) ? vsc_d[t - off] : 0;
        int d1 = vsc_d[t + 256 - off];
        int s0 = (t >= off) ? vsc_s[t - off] : 0;
        int s1 = vsc_s[t + 256 - off];
        __syncthreads();
        vsc_d[t] += d0; vsc_d[t + 256] += d1;
        vsc_s[t] += s0; vsc_s[t + 256] += s1;
        __syncthreads();
    }
    for (int b = t; b < NB; b += 256) {
        cur_d[b] = b ? vsc_d[b - 1] : 0;   // exclusive prefix = stage base
        cur_s[b] = b ? vsc_s[b - 1] : 0;
    }
    __syncthreads();
    // scatter into bucket-grouped LDS stage (re-read src/dst: L2-hit)
    for (int i = t; i < n; i += 256) {
        int s = src[e0 + i];
        int d = dst[e0 + i];
        int bd = d >> 8;
        int p = atomicAdd(&cur_d[bd], 1);
        stage_d[p] = ((unsigned)(d & 255) << 24) | (unsigned)s;
        bmap_d[p] = (unsigned short)bd;
        int bs = s >> 8;
        int ps = atomicAdd(&cur_s[bs], 1);
        stage_s[ps] = (unsigned char)(s & 255);
        bmap_s[ps] = (unsigned short)bs;
    }
    __syncthreads();
    // burst copy-out: consecutive threads hit consecutive slots of each run
    for (int i = t; i < n; i += 256) {
        int bd = bmap_d[i];
        int excl = bd ? vsc_d[bd - 1] : 0;
        int gp = hofs_d[bd] + (i - excl);
        if (gp < GCAP) bstore_d[(size_t)bd * GCAP + gp] = stage_d[i];
        int bs2 = bmap_s[i];
        int excl2 = bs2 ? vsc_s[bs2 - 1] : 0;
        int gp2 = hofs_s[bs2] + (i - excl2);
        if (gp2 < GCAP) bstore_s[(size_t)bs2 * GCAP + gp2] = stage_s[i];
    }
}

// ---------------------------------------------------------------------------
// K1: scan of per-bucket dst totals -> bucket_base[0..NB]; also row_start[N].
// ---------------------------------------------------------------------------
__global__ void scanb_kernel(const int* __restrict__ gcnt_d, int* __restrict__ bucket_base,
                             int* __restrict__ row_start) {
    __shared__ int v[512];
    int t = threadIdx.x;
    v[t] = (t < NB) ? min(gcnt_d[t], GCAP) : 0;
    __syncthreads();
    for (int off = 1; off < 512; off <<= 1) {
        int x = (t >= off) ? v[t - off] : 0;
        __syncthreads();
        v[t] += x;
        __syncthreads();
    }
    if (t < NB) bucket_base[t + 1] = v[t];
    if (t == 0) {
        bucket_base[0] = 0;
        row_start[N_NODES] = v[NB - 1];
    }
}

// ---------------------------------------------------------------------------
// K2: out-degree histogram per src-bucket -> rn_out (byte entries).
// ---------------------------------------------------------------------------
__global__ __launch_bounds__(256) void count_kernel(const int* __restrict__ gcnt_s,
                                                    const unsigned char* __restrict__ bstore_s,
                                                    float* __restrict__ rn_out) {
    __shared__ int lcnt[256];
    int b = blockIdx.x;
    int t = threadIdx.x;
    lcnt[t] = 0;
    __syncthreads();
    int cnt = min(gcnt_s[b], GCAP);
    const unsigned char* bs = &bstore_s[(size_t)b * GCAP];
    for (int i = t; i < cnt; i += 256)
        atomicAdd(&lcnt[bs[i]], 1);
    __syncthreads();
    int node = b * 256 + t;
    if (node < N_NODES)
        rn_out[node] = rsqrtf((float)max(lcnt[t], 1));
}

// ---------------------------------------------------------------------------
// K3: per-bucket CSR fill + rn_in + row_start (no global atomics).
// ---------------------------------------------------------------------------
__global__ __launch_bounds__(256) void fill2_kernel(const int* __restrict__ gcnt_d,
                                                    const unsigned* __restrict__ bstore_d,
                                                    const int* __restrict__ bucket_base,
                                                    int* __restrict__ col,
                                                    int* __restrict__ row_start,
                                                    float* __restrict__ rn_in) {
    __shared__ int lcnt[256];
    __shared__ int lpre[256];
    __shared__ int lcur[256];
    __shared__ int stage[GCAP];
    int b = blockIdx.x;
    int t = threadIdx.x;
    int node0 = b * 256;
    int nn = min(256, N_NODES - node0);
    lcnt[t] = 0;
    __syncthreads();
    int cnt = min(gcnt_d[b], GCAP);
    int base = bucket_base[b];
    const unsigned* bs = &bstore_d[(size_t)b * GCAP];
    for (int i = t; i < cnt; i += 256)
        atomicAdd(&lcnt[bs[i] >> 24], 1);
    __syncthreads();
    int myc = lcnt[t];
    lpre[t] = myc;
    __syncthreads();
    for (int off = 1; off < 256; off <<= 1) {
        int x = (t >= off) ? lpre[t - off] : 0;
        __syncthreads();
        lpre[t] += x;
        __syncthreads();
    }
    int excl = lpre[t] - myc;
    if (t < nn) {
        row_start[node0 + t] = base + excl;
        rn_in[node0 + t] = rsqrtf((float)max(myc, 1));
    }
    lcur[t] = excl;
    __syncthreads();
    for (int i = t; i < cnt; i += 256) {
        unsigned e = bs[i];
        int p = atomicAdd(&lcur[e >> 24], 1);
        stage[p] = (int)(e & 0xFFFFFF);
    }
    __syncthreads();
    for (int i = t; i < cnt; i += 256)
        col[base + i] = stage[i];
}

// ---------------------------------------------------------------------------
// K4a: pack weights as transposed bf16 W_t[n][k].
// ---------------------------------------------------------------------------
__global__ void packw_kernel(const float* __restrict__ W_h, const float* __restrict__ W_hf,
                             unsigned short* __restrict__ W1_t,
                             unsigned short* __restrict__ W23_t,
                             unsigned short* __restrict__ Wf_t) {
    int idx = blockIdx.x * 256 + threadIdx.x;
    if (idx < 16384) {
        int n = idx >> 7, k = idx & 127;
        W1_t[idx] = f2bf(W_h[k * 384 + n]);
    } else if (idx < 49152) {
        int j = idx - 16384;
        int n = j >> 7, k = j & 127;
        W23_t[j] = f2bf(W_h[k * 384 + 128 + n]);
    } else if (idx < 81920) {
        int j = idx - 49152;
        int n = j >> 7, k = j & 127;
        Wf_t[j] = f2bf(W_hf[k * 256 + n]);
    }
}

// ---------------------------------------------------------------------------
// K4b: hidden f32 -> bf16
// ---------------------------------------------------------------------------
__global__ __launch_bounds__(256) void packh_kernel(const float* __restrict__ hidden,
                                                    unsigned short* __restrict__ hidden_bf) {
    int i = (blockIdx.x * 256 + threadIdx.x) * 8;   // grid covers exactly N*128
    float4 a = *reinterpret_cast<const float4*>(&hidden[i]);
    float4 b = *reinterpret_cast<const float4*>(&hidden[i + 4]);
    ushort4 lo, hi;
    lo.x = f2bf(a.x); lo.y = f2bf(a.y); lo.z = f2bf(a.z); lo.w = f2bf(a.w);
    hi.x = f2bf(b.x); hi.y = f2bf(b.y); hi.z = f2bf(b.z); hi.w = f2bf(b.w);
    *reinterpret_cast<ushort4*>(&hidden_bf[i]) = lo;
    *reinterpret_cast<ushort4*>(&hidden_bf[i + 4]) = hi;
}

// ---------------------------------------------------------------------------
// K5: GEMM1 via MFMA — h1n = bf16( (hidden @ W_h[:,0:128]) * rn_out ).
// A-frags direct from global; all of W1_t (32 KB) staged once into LDS via
// global_load_lds, shared by all 4 waves, XOR-swizzled at 16B granularity.
// ---------------------------------------------------------------------------
__global__ __launch_bounds__(256) void gemm1_mfma(const unsigned short* __restrict__ hidden_bf,
                                                  const unsigned short* __restrict__ W1_t,
                                                  const float* __restrict__ rn_out,
                                                  unsigned short* __restrict__ h1n) {
    __shared__ __align__(16) unsigned short Bs[16384];   // 32 KB: [128 n-rows][16 granules]
    int t = threadIdx.x;
    int row0 = blockIdx.x * 64;
    int lane = t & 63;
    int wave = t >> 6;
    int wr0 = wave * 16;
    int m = lane & 15;
    int q = lane >> 4;

    // A-frags direct from global (row clamped; OOB rows' results are never stored)
    int arow = min(row0 + wr0 + m, N_NODES - 1);
    bf16x8 af[4];
#pragma unroll
    for (int kc = 0; kc < 4; ++kc)
        af[kc] = *reinterpret_cast<const bf16x8*>(&hidden_bf[arow * 128 + kc * 32 + q * 8]);
    float s4[4];
#pragma unroll
    for (int reg = 0; reg < 4; ++reg) {
        int row = row0 + wr0 + q * 4 + reg;
        s4[reg] = (row < N_NODES) ? rn_out[row] : 0.f;
    }

    // stage all of W1_t, swizzled: LDS granule (row, kseg) holds logical (row, kseg^(row&7))
#pragma unroll
    for (int i = 0; i < 8; ++i) {
        int G = i * 256 + t;            // granule 0..2047
        int row = G >> 4;
        int kseg = G & 15;
        gld_lds16(&W1_t[row * 128 + ((kseg ^ (row & 7)) * 8)], &Bs[G * 8]);
    }
    __syncthreads();   // barrier drains vmcnt -> staged B visible

    f32x4 accn[8];
#pragma unroll
    for (int nt = 0; nt < 8; ++nt) {
        f32x4 acc = {0.f, 0.f, 0.f, 0.f};
#pragma unroll
        for (int kc = 0; kc < 4; ++kc) {
            int g = (nt * 16 + m) * 16 + ((kc * 4 + q) ^ (m & 7));
            bf16x8 b = *reinterpret_cast<const bf16x8*>(&Bs[g * 8]);
            acc = __builtin_amdgcn_mfma_f32_16x16x32_bf16(af[kc], b, acc, 0, 0, 0);
        }
        accn[nt] = acc;
    }
    __syncthreads();   // all waves done reading Bs; reuse as bf16 output stage

    unsigned short (*Sg)[136] = reinterpret_cast<unsigned short (*)[136]>(&Bs[0]);  // 17408 B
#pragma unroll
    for (int nt = 0; nt < 8; ++nt)
#pragma unroll
        for (int reg = 0; reg < 4; ++reg)
            Sg[wr0 + q * 4 + reg][nt * 16 + m] = f2bf(accn[nt][reg] * s4[reg]);
    __syncthreads();
    // coalesced stream-out: 8 bf16 (int4) per access
    int seg = (t & 15) * 8;
    int rb = t >> 4;            // 0..15
#pragma unroll
    for (int i = 0; i < 4; ++i) {
        int r = rb + i * 16;
        int row = row0 + r;
        if (row < N_NODES)
            *reinterpret_cast<int4*>(&h1n[row * 128 + seg]) =
                *reinterpret_cast<const int4*>(&Sg[r][seg]);
    }
}

// ---------------------------------------------------------------------------
// K6: pull aggregation — one wave per dst node; writes conv as packed bf16.
// readlane SGPR broadcast + 16 loads in flight + split accumulators.
// (At the L2-miss/L3-service throughput wall: 351 MB random-gather re-fetch.)
// ---------------------------------------------------------------------------
__global__ __launch_bounds__(256) void aggregate_kernel(const unsigned* __restrict__ h1n,
                                                        const int* __restrict__ row_start,
                                                        const int* __restrict__ col,
                                                        const float* __restrict__ rn_in,
                                                        unsigned* __restrict__ conv_bf) {
    int wave = threadIdx.x >> 6;
    int lane = threadIdx.x & 63;
    int node = blockIdx.x * 4 + wave;
    if (node >= N_NODES) return;
    int start = row_start[node];
    int end = row_start[node + 1];
    float ax0 = 0.f, ax1 = 0.f, ay0 = 0.f, ay1 = 0.f;
    for (int j = start; j < end; j += 64) {
        int cnt = min(64, end - j);
        int myc = (lane < cnt) ? col[j + lane] : 0;
        int i = 0;
        for (; i + 16 <= cnt; i += 16) {
            unsigned u[16];
#pragma unroll
            for (int k = 0; k < 16; ++k) {
                int s = __builtin_amdgcn_readlane(myc, i + k);   // SGPR broadcast
                u[k] = h1n[s * 64 + lane];                       // saddr-form load
            }
#pragma unroll
            for (int k = 0; k < 16; k += 2) {
                ax0 += __uint_as_float(u[k] << 16);
                ay0 += __uint_as_float(u[k] & 0xFFFF0000u);
                ax1 += __uint_as_float(u[k + 1] << 16);
                ay1 += __uint_as_float(u[k + 1] & 0xFFFF0000u);
            }
        }
        for (; i + 4 <= cnt; i += 4) {
            unsigned u[4];
#pragma unroll
            for (int k = 0; k < 4; ++k) {
                int s = __builtin_amdgcn_readlane(myc, i + k);
                u[k] = h1n[s * 64 + lane];
            }
#pragma unroll
            for (int k = 0; k < 4; k += 2) {
                ax0 += __uint_as_float(u[k] << 16);
                ay0 += __uint_as_float(u[k] & 0xFFFF0000u);
                ax1 += __uint_as_float(u[k + 1] << 16);
                ay1 += __uint_as_float(u[k + 1] & 0xFFFF0000u);
            }
        }
        for (; i < cnt; ++i) {
            int s = __builtin_amdgcn_readlane(myc, i);
            unsigned u = h1n[s * 64 + lane];
            ax0 += __uint_as_float(u << 16);
            ay0 += __uint_as_float(u & 0xFFFF0000u);
        }
    }
    float rn = rn_in[node];
    float ax = ax0 + ax1, ay = ay0 + ay1;
    unsigned packed = ((unsigned)f2bf(ay * rn) << 16) | (unsigned)f2bf(ax * rn);
    conv_bf[node * 64 + lane] = packed;
}

// ---------------------------------------------------------------------------
// K7: fused final via MFMA. A-frags (hidden + conv) direct from global;
// B (4 weight tiles per nt) staged in LDS per nt, double-buffered with
// global_load_lds. 16B-granule XOR swizzle. Output stored directly.
// ---------------------------------------------------------------------------
__global__ __launch_bounds__(256) void final_mfma(const unsigned short* __restrict__ hidden_bf,
                                                  const unsigned short* __restrict__ conv_bf,
                                                  const unsigned short* __restrict__ W23_t,
                                                  const unsigned short* __restrict__ Wf_t,
                                                  float* __restrict__ out) {
    __shared__ __align__(16) unsigned short Bst[2][8192];   // 2 x 16 KB (4 tiles x 16 x 128)
    int t = threadIdx.x;
    int row0 = blockIdx.x * 64;
    int lane = t & 63;
    int wave = t >> 6;
    int wr0 = wave * 16;
    int m = lane & 15;
    int q = lane >> 4;

    // A-frags direct from global (clamped row; OOB rows never stored)
    int arow = min(row0 + wr0 + m, N_NODES - 1);
    bf16x8 ah[4], ac[4];
#pragma unroll
    for (int kc = 0; kc < 4; ++kc) {
        int o = arow * 128 + kc * 32 + q * 8;
        ah[kc] = *reinterpret_cast<const bf16x8*>(&hidden_bf[o]);
        ac[kc] = *reinterpret_cast<const bf16x8*>(&conv_bf[o]);
    }

    // stage the 4 weight tiles for column-slice nt into buf (16 KB):
    // granule G = mat*256 + rowin*16 + kseg; content = logical kseg^(rowin&7)
    auto stage = [&](int nt, int buf) {
#pragma unroll
        for (int i = 0; i < 4; ++i) {           // mat = i (0:W23 nt, 1:W23 nt+8, 2:Wf nt, 3:Wf nt+8)
            int rowin = t >> 4;                 // 0..15
            int kseg = t & 15;
            int srow = ((i & 1) ? (nt + 8) : nt) * 16 + rowin;
            const unsigned short* Wp = (i < 2) ? W23_t : Wf_t;
            gld_lds16(&Wp[srow * 128 + ((kseg ^ (rowin & 7)) * 8)],
                      &Bst[buf][(i * 256 + t) * 8]);
        }
    };

    stage(0, 0);
    __syncthreads();   // drains vmcnt -> buf0 ready

#pragma unroll
    for (int nt = 0; nt < 8; ++nt) {
        if (nt < 7) stage(nt + 1, (nt + 1) & 1);     // prefetch next tile into other buffer
        const unsigned short* Bb = Bst[nt & 1];
        f32x4 h2 = {0.f, 0.f, 0.f, 0.f}, h3 = {0.f, 0.f, 0.f, 0.f};
        f32x4 f1 = {0.f, 0.f, 0.f, 0.f}, f2 = {0.f, 0.f, 0.f, 0.f};
#pragma unroll
        for (int kc = 0; kc < 4; ++kc) {
            int ks = (kc * 4 + q) ^ (m & 7);
            bf16x8 b2  = *reinterpret_cast<const bf16x8*>(&Bb[(0 * 256 + m * 16 + ks) * 8]);
            bf16x8 b3  = *reinterpret_cast<const bf16x8*>(&Bb[(1 * 256 + m * 16 + ks) * 8]);
            bf16x8 bf1 = *reinterpret_cast<const bf16x8*>(&Bb[(2 * 256 + m * 16 + ks) * 8]);
            bf16x8 bf2 = *reinterpret_cast<const bf16x8*>(&Bb[(3 * 256 + m * 16 + ks) * 8]);
            h2 = __builtin_amdgcn_mfma_f32_16x16x32_bf16(ah[kc], b2, h2, 0, 0, 0);
            h3 = __builtin_amdgcn_mfma_f32_16x16x32_bf16(ah[kc], b3, h3, 0, 0, 0);
            f1 = __builtin_amdgcn_mfma_f32_16x16x32_bf16(ac[kc], bf1, f1, 0, 0, 0);
            f2 = __builtin_amdgcn_mfma_f32_16x16x32_bf16(ac[kc], bf2, f2, 0, 0, 0);
        }
        int colb = nt * 16 + m;
#pragma unroll
        for (int reg = 0; reg < 4; ++reg) {
            int row = row0 + wr0 + q * 4 + reg;
            float g = fmaxf(f1[reg] + h2[reg], 0.f);
            float o = h3[reg] + g * f2[reg];
            if (row < N_NODES) {
                out[(size_t)row * 128 + colb] = o;
                out[(size_t)(N_NODES + row) * 128 + colb] = o;
            }
        }
        __syncthreads();   // all waves done with buf[nt&1]; prefetch drained for next iter
    }
}

// ---------------------------------------------------------------------------
// launch
// ---------------------------------------------------------------------------
extern "C" void kernel_launch(void* const* d_in, const int* in_sizes, int n_in,
                              void* d_out, int out_size, void* d_ws, size_t ws_size,
                              hipStream_t stream) {
    const float* hidden = (const float*)d_in[0];
    const int* src = (const int*)d_in[1];
    const int* dst = (const int*)d_in[2];
    const float* W_h = (const float*)d_in[3];
    const float* W_hf = (const float*)d_in[4];
    float* out = (float*)d_out;

    auto align_up = [](size_t x) { return (x + 255) & ~(size_t)255; };
    char* p = (char*)d_ws;
    size_t off = 0;
    unsigned short* h1n = (unsigned short*)(p + off); off += align_up((size_t)N_NODES * 128 * 2);
    unsigned short* conv_bf = (unsigned short*)(p + off); off += align_up((size_t)N_NODES * 128 * 2);
    unsigned short* hidden_bf = (unsigned short*)(p + off); off += align_up((size_t)N_NODES * 128 * 2);
    int* col = (int*)(p + off); off += align_up((size_t)N_EDGES * 4);
    unsigned* bstore_d = (unsigned*)(p + off); off += align_up((size_t)NB * GCAP * 4);
    unsigned char* bstore_s = (unsigned char*)(p + off); off += align_up((size_t)NB * GCAP);
    int* gcnt_d = (int*)(p + off); off += align_up((size_t)NB * 4);
    int* gcnt_s = (int*)(p + off); off += align_up((size_t)NB * 4);
    int* bucket_base = (int*)(p + off); off += align_up((size_t)(NB + 1) * 4);
    int* row_start = (int*)(p + off); off += align_up((size_t)(N_NODES + 1) * 4);
    float* rn_out = (float*)(p + off); off += align_up((size_t)N_NODES * 4);
    float* rn_in = (float*)(p + off); off += align_up((size_t)N_NODES * 4);
    unsigned short* W1_t = (unsigned short*)(p + off); off += align_up((size_t)128 * 128 * 2);
    unsigned short* W23_t = (unsigned short*)(p + off); off += align_up((size_t)256 * 128 * 2);
    unsigned short* Wf_t = (unsigned short*)(p + off); off += align_up((size_t)256 * 128 * 2);

    (void)hipMemsetAsync(gcnt_d, 0, (size_t)NB * 4, stream);
    (void)hipMemsetAsync(gcnt_s, 0, (size_t)NB * 4, stream);

    partition_kernel<<<(N_EDGES + PCHUNK - 1) / PCHUNK, 256, 0, stream>>>(
        src, dst, gcnt_d, gcnt_s, bstore_d, bstore_s);
    scanb_kernel<<<1, 512, 0, stream>>>(gcnt_d, bucket_base, row_start);
    count_kernel<<<NB, 256, 0, stream>>>(gcnt_s, bstore_s, rn_out);
    fill2_kernel<<<NB, 256, 0, stream>>>(gcnt_d, bstore_d, bucket_base, col, row_start, rn_in);
    packw_kernel<<<(81920 + 255) / 256, 256, 0, stream>>>(W_h, W_hf, W1_t, W23_t, Wf_t);
    packh_kernel<<<(N_NODES * 128) / (256 * 8), 256, 0, stream>>>(hidden, hidden_bf);
    gemm1_mfma<<<(N_NODES + 63) / 64, 256, 0, stream>>>(hidden_bf, W1_t, rn_out, h1n);
    aggregate_kernel<<<(N_NODES + 3) / 4, 256, 0, stream>>>(
        (const unsigned*)h1n, row_start, col, rn_in, (unsigned*)conv_bf);
    final_mfma<<<(N_NODES + 63) / 64, 256, 0, stream>>>(hidden_bf, conv_bf, W23_t, Wf_t, out);
}

// Round 5
// 412.521 us; speedup vs baseline: 1.3196x; 1.0156x over previous
//
#include <hip/hip_runtime.h>

#define N_NODES 100000
#define N_EDGES 3200000
#define DIM 128

#define NB 391        // ceil(100000/256) buckets of 256 nodes
#define GCAP 9216     // per-bucket capacity; mean 8192, sigma ~90 (11 sigma)
#define PCHUNK 4096   // edges per partition block (782 blocks)

typedef __attribute__((ext_vector_type(8))) short bf16x8;   // 8 bf16 = 4 VGPRs
typedef __attribute__((ext_vector_type(4))) float f32x4;    // MFMA acc

// ---------------------------------------------------------------------------
// helpers
// ---------------------------------------------------------------------------
__device__ __forceinline__ unsigned short f2bf(float x) {
    unsigned u = __float_as_uint(x);
    unsigned r = (u + 0x7FFF + ((u >> 16) & 1)) >> 16;  // round-nearest-even
    return (unsigned short)r;
}

// load 8 consecutive f32 and convert to a bf16x8 fragment (same f2bf as the
// old packh path -> bit-identical numerics)
__device__ __forceinline__ bf16x8 load_bf8(const float* __restrict__ p) {
    float4 a0 = *reinterpret_cast<const float4*>(p);
    float4 a1 = *reinterpret_cast<const float4*>(p + 4);
    bf16x8 v;
    v[0] = (short)f2bf(a0.x); v[1] = (short)f2bf(a0.y);
    v[2] = (short)f2bf(a0.z); v[3] = (short)f2bf(a0.w);
    v[4] = (short)f2bf(a1.x); v[5] = (short)f2bf(a1.y);
    v[6] = (short)f2bf(a1.z); v[7] = (short)f2bf(a1.w);
    return v;
}

// async global->LDS, 16B per lane (dest must be linear: base + lane*16)
__device__ __forceinline__ void gld_lds16(const unsigned short* src, unsigned short* dst) {
    __builtin_amdgcn_global_load_lds(
        (const __attribute__((address_space(1))) unsigned int*)src,
        (__attribute__((address_space(3))) unsigned int*)dst, 16, 0, 0);
}

// ---------------------------------------------------------------------------
// K0: dual partition (dst-buckets for CSR + src-buckets for out-degree).
// stage-then-burst: per-block LDS histogram -> block-local prefix scan ->
// scatter into bucket-GROUPED LDS stage -> single coalesced burst copy-out.
// (verified r4: write-amp gone, kernel left the top-5 — unchanged)
// ---------------------------------------------------------------------------
__global__ __launch_bounds__(256) void partition_kernel(const int* __restrict__ src,
                                                        const int* __restrict__ dst,
                                                        int* __restrict__ gcnt_d,
                                                        int* __restrict__ gcnt_s,
                                                        unsigned* __restrict__ bstore_d,
                                                        unsigned char* __restrict__ bstore_s) {
    __shared__ int hist_d[NB], cur_d[NB], hofs_d[NB];
    __shared__ int hist_s[NB], cur_s[NB], hofs_s[NB];
    __shared__ int vsc_d[512], vsc_s[512];          // inclusive scans
    __shared__ unsigned stage_d[PCHUNK];            // bucket-grouped entries
    __shared__ unsigned short bmap_d[PCHUNK];       // slot -> bucket
    __shared__ unsigned char stage_s[PCHUNK];
    __shared__ unsigned short bmap_s[PCHUNK];
    int t = threadIdx.x;
    for (int b = t; b < NB; b += 256) { hist_d[b] = 0; hist_s[b] = 0; }
    __syncthreads();
    int e0 = blockIdx.x * PCHUNK;
    int n = min(PCHUNK, N_EDGES - e0);
    for (int i = t; i < n; i += 256) {
        int s = src[e0 + i];
        int d = dst[e0 + i];
        atomicAdd(&hist_d[d >> 8], 1);
        atomicAdd(&hist_s[s >> 8], 1);
    }
    __syncthreads();
    // global range reservation (unchanged semantics)
    for (int b = t; b < NB; b += 256) {
        hofs_d[b] = (hist_d[b] > 0) ? atomicAdd(&gcnt_d[b], hist_d[b]) : 0;
        hofs_s[b] = (hist_s[b] > 0) ? atomicAdd(&gcnt_s[b], hist_s[b]) : 0;
    }
    // block-local inclusive scan over NB buckets (512 slots, 2 per thread)
    vsc_d[t]       = (t < NB) ? hist_d[t] : 0;
    vsc_d[t + 256] = (t + 256 < NB) ? hist_d[t + 256] : 0;
    vsc_s[t]       = (t < NB) ? hist_s[t] : 0;
    vsc_s[t + 256] = (t + 256 < NB) ? hist_s[t + 256] : 0;
    __syncthreads();
    for (int off = 1; off < 512; off <<= 1) {
        int d0 = (t >= off) ? vsc_d[t - off] : 0;
        int d1 = vsc_d[t + 256 - off];
        int s0 = (t >= off) ? vsc_s[t - off] : 0;
        int s1 = vsc_s[t + 256 - off];
        __syncthreads();
        vsc_d[t] += d0; vsc_d[t + 256] += d1;
        vsc_s[t] += s0; vsc_s[t + 256] += s1;
        __syncthreads();
    }
    for (int b = t; b < NB; b += 256) {
        cur_d[b] = b ? vsc_d[b - 1] : 0;   // exclusive prefix = stage base
        cur_s[b] = b ? vsc_s[b - 1] : 0;
    }
    __syncthreads();
    // scatter into bucket-grouped LDS stage (re-read src/dst: L2-hit)
    for (int i = t; i < n; i += 256) {
        int s = src[e0 + i];
        int d = dst[e0 + i];
        int bd = d >> 8;
        int p = atomicAdd(&cur_d[bd], 1);
        stage_d[p] = ((unsigned)(d & 255) << 24) | (unsigned)s;
        bmap_d[p] = (unsigned short)bd;
        int bs = s >> 8;
        int ps = atomicAdd(&cur_s[bs], 1);
        stage_s[ps] = (unsigned char)(s & 255);
        bmap_s[ps] = (unsigned short)bs;
    }
    __syncthreads();
    // burst copy-out: consecutive threads hit consecutive slots of each run
    for (int i = t; i < n; i += 256) {
        int bd = bmap_d[i];
        int excl = bd ? vsc_d[bd - 1] : 0;
        int gp = hofs_d[bd] + (i - excl);
        if (gp < GCAP) bstore_d[(size_t)bd * GCAP + gp] = stage_d[i];
        int bs2 = bmap_s[i];
        int excl2 = bs2 ? vsc_s[bs2 - 1] : 0;
        int gp2 = hofs_s[bs2] + (i - excl2);
        if (gp2 < GCAP) bstore_s[(size_t)bs2 * GCAP + gp2] = stage_s[i];
    }
}

// ---------------------------------------------------------------------------
// K1: scan of per-bucket dst totals -> bucket_base[0..NB]; also row_start[N].
// ---------------------------------------------------------------------------
__global__ void scanb_kernel(const int* __restrict__ gcnt_d, int* __restrict__ bucket_base,
                             int* __restrict__ row_start) {
    __shared__ int v[512];
    int t = threadIdx.x;
    v[t] = (t < NB) ? min(gcnt_d[t], GCAP) : 0;
    __syncthreads();
    for (int off = 1; off < 512; off <<= 1) {
        int x = (t >= off) ? v[t - off] : 0;
        __syncthreads();
        v[t] += x;
        __syncthreads();
    }
    if (t < NB) bucket_base[t + 1] = v[t];
    if (t == 0) {
        bucket_base[0] = 0;
        row_start[N_NODES] = v[NB - 1];
    }
}

// ---------------------------------------------------------------------------
// K2: out-degree histogram per src-bucket -> rn_out (byte entries).
// ---------------------------------------------------------------------------
__global__ __launch_bounds__(256) void count_kernel(const int* __restrict__ gcnt_s,
                                                    const unsigned char* __restrict__ bstore_s,
                                                    float* __restrict__ rn_out) {
    __shared__ int lcnt[256];
    int b = blockIdx.x;
    int t = threadIdx.x;
    lcnt[t] = 0;
    __syncthreads();
    int cnt = min(gcnt_s[b], GCAP);
    const unsigned char* bs = &bstore_s[(size_t)b * GCAP];
    for (int i = t; i < cnt; i += 256)
        atomicAdd(&lcnt[bs[i]], 1);
    __syncthreads();
    int node = b * 256 + t;
    if (node < N_NODES)
        rn_out[node] = rsqrtf((float)max(lcnt[t], 1));
}

// ---------------------------------------------------------------------------
// K3: per-bucket CSR fill + rn_in + row_start (no global atomics).
// ---------------------------------------------------------------------------
__global__ __launch_bounds__(256) void fill2_kernel(const int* __restrict__ gcnt_d,
                                                    const unsigned* __restrict__ bstore_d,
                                                    const int* __restrict__ bucket_base,
                                                    int* __restrict__ col,
                                                    int* __restrict__ row_start,
                                                    float* __restrict__ rn_in) {
    __shared__ int lcnt[256];
    __shared__ int lpre[256];
    __shared__ int lcur[256];
    __shared__ int stage[GCAP];
    int b = blockIdx.x;
    int t = threadIdx.x;
    int node0 = b * 256;
    int nn = min(256, N_NODES - node0);
    lcnt[t] = 0;
    __syncthreads();
    int cnt = min(gcnt_d[b], GCAP);
    int base = bucket_base[b];
    const unsigned* bs = &bstore_d[(size_t)b * GCAP];
    for (int i = t; i < cnt; i += 256)
        atomicAdd(&lcnt[bs[i] >> 24], 1);
    __syncthreads();
    int myc = lcnt[t];
    lpre[t] = myc;
    __syncthreads();
    for (int off = 1; off < 256; off <<= 1) {
        int x = (t >= off) ? lpre[t - off] : 0;
        __syncthreads();
        lpre[t] += x;
        __syncthreads();
    }
    int excl = lpre[t] - myc;
    if (t < nn) {
        row_start[node0 + t] = base + excl;
        rn_in[node0 + t] = rsqrtf((float)max(myc, 1));
    }
    lcur[t] = excl;
    __syncthreads();
    for (int i = t; i < cnt; i += 256) {
        unsigned e = bs[i];
        int p = atomicAdd(&lcur[e >> 24], 1);
        stage[p] = (int)(e & 0xFFFFFF);
    }
    __syncthreads();
    for (int i = t; i < cnt; i += 256)
        col[base + i] = stage[i];
}

// ---------------------------------------------------------------------------
// K4a: pack weights as transposed bf16 W_t[n][k].
// ---------------------------------------------------------------------------
__global__ void packw_kernel(const float* __restrict__ W_h, const float* __restrict__ W_hf,
                             unsigned short* __restrict__ W1_t,
                             unsigned short* __restrict__ W23_t,
                             unsigned short* __restrict__ Wf_t) {
    int idx = blockIdx.x * 256 + threadIdx.x;
    if (idx < 16384) {
        int n = idx >> 7, k = idx & 127;
        W1_t[idx] = f2bf(W_h[k * 384 + n]);
    } else if (idx < 49152) {
        int j = idx - 16384;
        int n = j >> 7, k = j & 127;
        W23_t[j] = f2bf(W_h[k * 384 + 128 + n]);
    } else if (idx < 81920) {
        int j = idx - 49152;
        int n = j >> 7, k = j & 127;
        Wf_t[j] = f2bf(W_hf[k * 256 + n]);
    }
}

// ---------------------------------------------------------------------------
// K5: GEMM1 via MFMA — h1n = bf16( (hidden @ W_h[:,0:128]) * rn_out ).
// v3: packh eliminated — A-frags loaded as f32 directly from hidden and
// converted in-reg (same f2bf -> bit-identical). W1_t staged once into LDS
// via global_load_lds, shared by all 4 waves, XOR-swizzled at 16B granules.
// ---------------------------------------------------------------------------
__global__ __launch_bounds__(256) void gemm1_mfma(const float* __restrict__ hidden,
                                                  const unsigned short* __restrict__ W1_t,
                                                  const float* __restrict__ rn_out,
                                                  unsigned short* __restrict__ h1n) {
    __shared__ __align__(16) unsigned short Bs[16384];   // 32 KB: [128 n-rows][16 granules]
    int t = threadIdx.x;
    int row0 = blockIdx.x * 64;
    int lane = t & 63;
    int wave = t >> 6;
    int wr0 = wave * 16;
    int m = lane & 15;
    int q = lane >> 4;

    // A-frags direct from f32 hidden (row clamped; OOB results never stored)
    int arow = min(row0 + wr0 + m, N_NODES - 1);
    bf16x8 af[4];
#pragma unroll
    for (int kc = 0; kc < 4; ++kc)
        af[kc] = load_bf8(&hidden[(size_t)arow * 128 + kc * 32 + q * 8]);
    float s4[4];
#pragma unroll
    for (int reg = 0; reg < 4; ++reg) {
        int row = row0 + wr0 + q * 4 + reg;
        s4[reg] = (row < N_NODES) ? rn_out[row] : 0.f;
    }

    // stage all of W1_t, swizzled: LDS granule (row, kseg) holds logical (row, kseg^(row&7))
#pragma unroll
    for (int i = 0; i < 8; ++i) {
        int G = i * 256 + t;            // granule 0..2047
        int row = G >> 4;
        int kseg = G & 15;
        gld_lds16(&W1_t[row * 128 + ((kseg ^ (row & 7)) * 8)], &Bs[G * 8]);
    }
    __syncthreads();   // barrier drains vmcnt -> staged B visible

    f32x4 accn[8];
#pragma unroll
    for (int nt = 0; nt < 8; ++nt) {
        f32x4 acc = {0.f, 0.f, 0.f, 0.f};
#pragma unroll
        for (int kc = 0; kc < 4; ++kc) {
            int g = (nt * 16 + m) * 16 + ((kc * 4 + q) ^ (m & 7));
            bf16x8 b = *reinterpret_cast<const bf16x8*>(&Bs[g * 8]);
            acc = __builtin_amdgcn_mfma_f32_16x16x32_bf16(af[kc], b, acc, 0, 0, 0);
        }
        accn[nt] = acc;
    }
    __syncthreads();   // all waves done reading Bs; reuse as bf16 output stage

    unsigned short (*Sg)[136] = reinterpret_cast<unsigned short (*)[136]>(&Bs[0]);  // 17408 B
#pragma unroll
    for (int nt = 0; nt < 8; ++nt)
#pragma unroll
        for (int reg = 0; reg < 4; ++reg)
            Sg[wr0 + q * 4 + reg][nt * 16 + m] = f2bf(accn[nt][reg] * s4[reg]);
    __syncthreads();
    // coalesced stream-out: 8 bf16 (int4) per access
    int seg = (t & 15) * 8;
    int rb = t >> 4;            // 0..15
#pragma unroll
    for (int i = 0; i < 4; ++i) {
        int r = rb + i * 16;
        int row = row0 + r;
        if (row < N_NODES)
            *reinterpret_cast<int4*>(&h1n[row * 128 + seg]) =
                *reinterpret_cast<const int4*>(&Sg[r][seg]);
    }
}

// ---------------------------------------------------------------------------
// K6: pull aggregation — one wave per dst node; writes conv as packed bf16.
// v5: 32 loads in flight (software-pipelined 2x16) — falsification probe for
// the L3-service-wall theory. readlane SGPR broadcast; split accumulators.
// ---------------------------------------------------------------------------
__global__ __launch_bounds__(256) void aggregate_kernel(const unsigned* __restrict__ h1n,
                                                        const int* __restrict__ row_start,
                                                        const int* __restrict__ col,
                                                        const float* __restrict__ rn_in,
                                                        unsigned* __restrict__ conv_bf) {
    int wave = threadIdx.x >> 6;
    int lane = threadIdx.x & 63;
    int node = blockIdx.x * 4 + wave;
    if (node >= N_NODES) return;
    int start = row_start[node];
    int end = row_start[node + 1];
    float ax0 = 0.f, ax1 = 0.f, ay0 = 0.f, ay1 = 0.f;
    for (int j = start; j < end; j += 64) {
        int cnt = min(64, end - j);
        int myc = (lane < cnt) ? col[j + lane] : 0;
        int i = 0;
        for (; i + 32 <= cnt; i += 32) {
            unsigned u[16], v[16];
#pragma unroll
            for (int k = 0; k < 16; ++k) {
                int s = __builtin_amdgcn_readlane(myc, i + k);
                u[k] = h1n[s * 64 + lane];
            }
#pragma unroll
            for (int k = 0; k < 16; ++k) {
                int s = __builtin_amdgcn_readlane(myc, i + 16 + k);
                v[k] = h1n[s * 64 + lane];
            }
#pragma unroll
            for (int k = 0; k < 16; k += 2) {
                ax0 += __uint_as_float(u[k] << 16);
                ay0 += __uint_as_float(u[k] & 0xFFFF0000u);
                ax1 += __uint_as_float(u[k + 1] << 16);
                ay1 += __uint_as_float(u[k + 1] & 0xFFFF0000u);
            }
#pragma unroll
            for (int k = 0; k < 16; k += 2) {
                ax0 += __uint_as_float(v[k] << 16);
                ay0 += __uint_as_float(v[k] & 0xFFFF0000u);
                ax1 += __uint_as_float(v[k + 1] << 16);
                ay1 += __uint_as_float(v[k + 1] & 0xFFFF0000u);
            }
        }
        for (; i + 16 <= cnt; i += 16) {
            unsigned u[16];
#pragma unroll
            for (int k = 0; k < 16; ++k) {
                int s = __builtin_amdgcn_readlane(myc, i + k);
                u[k] = h1n[s * 64 + lane];
            }
#pragma unroll
            for (int k = 0; k < 16; k += 2) {
                ax0 += __uint_as_float(u[k] << 16);
                ay0 += __uint_as_float(u[k] & 0xFFFF0000u);
                ax1 += __uint_as_float(u[k + 1] << 16);
                ay1 += __uint_as_float(u[k + 1] & 0xFFFF0000u);
            }
        }
        for (; i + 4 <= cnt; i += 4) {
            unsigned u[4];
#pragma unroll
            for (int k = 0; k < 4; ++k) {
                int s = __builtin_amdgcn_readlane(myc, i + k);
                u[k] = h1n[s * 64 + lane];
            }
#pragma unroll
            for (int k = 0; k < 4; k += 2) {
                ax0 += __uint_as_float(u[k] << 16);
                ay0 += __uint_as_float(u[k] & 0xFFFF0000u);
                ax1 += __uint_as_float(u[k + 1] << 16);
                ay1 += __uint_as_float(u[k + 1] & 0xFFFF0000u);
            }
        }
        for (; i < cnt; ++i) {
            int s = __builtin_amdgcn_readlane(myc, i);
            unsigned u = h1n[s * 64 + lane];
            ax0 += __uint_as_float(u << 16);
            ay0 += __uint_as_float(u & 0xFFFF0000u);
        }
    }
    float rn = rn_in[node];
    float ax = ax0 + ax1, ay = ay0 + ay1;
    unsigned packed = ((unsigned)f2bf(ay * rn) << 16) | (unsigned)f2bf(ax * rn);
    conv_bf[node * 64 + lane] = packed;
}

// ---------------------------------------------------------------------------
// K7: fused final via MFMA. v3: packh eliminated — hidden A-frags loaded as
// f32 direct from hidden and converted in-reg; conv A-frags stay bf16.
// B (4 weight tiles per nt) staged in LDS per nt, double-buffered with
// global_load_lds. 16B-granule XOR swizzle. Output stored directly.
// ---------------------------------------------------------------------------
__global__ __launch_bounds__(256) void final_mfma(const float* __restrict__ hidden,
                                                  const unsigned short* __restrict__ conv_bf,
                                                  const unsigned short* __restrict__ W23_t,
                                                  const unsigned short* __restrict__ Wf_t,
                                                  float* __restrict__ out) {
    __shared__ __align__(16) unsigned short Bst[2][8192];   // 2 x 16 KB (4 tiles x 16 x 128)
    int t = threadIdx.x;
    int row0 = blockIdx.x * 64;
    int lane = t & 63;
    int wave = t >> 6;
    int wr0 = wave * 16;
    int m = lane & 15;
    int q = lane >> 4;

    // A-frags direct from global (clamped row; OOB rows never stored)
    int arow = min(row0 + wr0 + m, N_NODES - 1);
    bf16x8 ah[4], ac[4];
#pragma unroll
    for (int kc = 0; kc < 4; ++kc) {
        int o = arow * 128 + kc * 32 + q * 8;
        ah[kc] = load_bf8(&hidden[(size_t)o]);
        ac[kc] = *reinterpret_cast<const bf16x8*>(&conv_bf[o]);
    }

    // stage the 4 weight tiles for column-slice nt into buf (16 KB):
    // granule G = mat*256 + rowin*16 + kseg; content = logical kseg^(rowin&7)
    auto stage = [&](int nt, int buf) {
#pragma unroll
        for (int i = 0; i < 4; ++i) {           // mat = i (0:W23 nt, 1:W23 nt+8, 2:Wf nt, 3:Wf nt+8)
            int rowin = t >> 4;                 // 0..15
            int kseg = t & 15;
            int srow = ((i & 1) ? (nt + 8) : nt) * 16 + rowin;
            const unsigned short* Wp = (i < 2) ? W23_t : Wf_t;
            gld_lds16(&Wp[srow * 128 + ((kseg ^ (rowin & 7)) * 8)],
                      &Bst[buf][(i * 256 + t) * 8]);
        }
    };

    stage(0, 0);
    __syncthreads();   // drains vmcnt -> buf0 ready

#pragma unroll
    for (int nt = 0; nt < 8; ++nt) {
        if (nt < 7) stage(nt + 1, (nt + 1) & 1);     // prefetch next tile into other buffer
        const unsigned short* Bb = Bst[nt & 1];
        f32x4 h2 = {0.f, 0.f, 0.f, 0.f}, h3 = {0.f, 0.f, 0.f, 0.f};
        f32x4 f1 = {0.f, 0.f, 0.f, 0.f}, f2 = {0.f, 0.f, 0.f, 0.f};
#pragma unroll
        for (int kc = 0; kc < 4; ++kc) {
            int ks = (kc * 4 + q) ^ (m & 7);
            bf16x8 b2  = *reinterpret_cast<const bf16x8*>(&Bb[(0 * 256 + m * 16 + ks) * 8]);
            bf16x8 b3  = *reinterpret_cast<const bf16x8*>(&Bb[(1 * 256 + m * 16 + ks) * 8]);
            bf16x8 bf1 = *reinterpret_cast<const bf16x8*>(&Bb[(2 * 256 + m * 16 + ks) * 8]);
            bf16x8 bf2 = *reinterpret_cast<const bf16x8*>(&Bb[(3 * 256 + m * 16 + ks) * 8]);
            h2 = __builtin_amdgcn_mfma_f32_16x16x32_bf16(ah[kc], b2, h2, 0, 0, 0);
            h3 = __builtin_amdgcn_mfma_f32_16x16x32_bf16(ah[kc], b3, h3, 0, 0, 0);
            f1 = __builtin_amdgcn_mfma_f32_16x16x32_bf16(ac[kc], bf1, f1, 0, 0, 0);
            f2 = __builtin_amdgcn_mfma_f32_16x16x32_bf16(ac[kc], bf2, f2, 0, 0, 0);
        }
        int colb = nt * 16 + m;
#pragma unroll
        for (int reg = 0; reg < 4; ++reg) {
            int row = row0 + wr0 + q * 4 + reg;
            float g = fmaxf(f1[reg] + h2[reg], 0.f);
            float o = h3[reg] + g * f2[reg];
            if (row < N_NODES) {
                out[(size_t)row * 128 + colb] = o;
                out[(size_t)(N_NODES + row) * 128 + colb] = o;
            }
        }
        __syncthreads();   // all waves done with buf[nt&1]; prefetch drained for next iter
    }
}

// ---------------------------------------------------------------------------
// launch
// ---------------------------------------------------------------------------
extern "C" void kernel_launch(void* const* d_in, const int* in_sizes, int n_in,
                              void* d_out, int out_size, void* d_ws, size_t ws_size,
                              hipStream_t stream) {
    const float* hidden = (const float*)d_in[0];
    const int* src = (const int*)d_in[1];
    const int* dst = (const int*)d_in[2];
    const float* W_h = (const float*)d_in[3];
    const float* W_hf = (const float*)d_in[4];
    float* out = (float*)d_out;

    auto align_up = [](size_t x) { return (x + 255) & ~(size_t)255; };
    char* p = (char*)d_ws;
    size_t off = 0;
    unsigned short* h1n = (unsigned short*)(p + off); off += align_up((size_t)N_NODES * 128 * 2);
    unsigned short* conv_bf = (unsigned short*)(p + off); off += align_up((size_t)N_NODES * 128 * 2);
    int* col = (int*)(p + off); off += align_up((size_t)N_EDGES * 4);
    unsigned* bstore_d = (unsigned*)(p + off); off += align_up((size_t)NB * GCAP * 4);
    unsigned char* bstore_s = (unsigned char*)(p + off); off += align_up((size_t)NB * GCAP);
    int* gcnt_d = (int*)(p + off); off += align_up((size_t)NB * 4);
    int* gcnt_s = (int*)(p + off); off += align_up((size_t)NB * 4);
    int* bucket_base = (int*)(p + off); off += align_up((size_t)(NB + 1) * 4);
    int* row_start = (int*)(p + off); off += align_up((size_t)(N_NODES + 1) * 4);
    float* rn_out = (float*)(p + off); off += align_up((size_t)N_NODES * 4);
    float* rn_in = (float*)(p + off); off += align_up((size_t)N_NODES * 4);
    unsigned short* W1_t = (unsigned short*)(p + off); off += align_up((size_t)128 * 128 * 2);
    unsigned short* W23_t = (unsigned short*)(p + off); off += align_up((size_t)256 * 128 * 2);
    unsigned short* Wf_t = (unsigned short*)(p + off); off += align_up((size_t)256 * 128 * 2);

    (void)hipMemsetAsync(gcnt_d, 0, (size_t)NB * 4, stream);
    (void)hipMemsetAsync(gcnt_s, 0, (size_t)NB * 4, stream);

    partition_kernel<<<(N_EDGES + PCHUNK - 1) / PCHUNK, 256, 0, stream>>>(
        src, dst, gcnt_d, gcnt_s, bstore_d, bstore_s);
    scanb_kernel<<<1, 512, 0, stream>>>(gcnt_d, bucket_base, row_start);
    count_kernel<<<NB, 256, 0, stream>>>(gcnt_s, bstore_s, rn_out);
    fill2_kernel<<<NB, 256, 0, stream>>>(gcnt_d, bstore_d, bucket_base, col, row_start, rn_in);
    packw_kernel<<<(81920 + 255) / 256, 256, 0, stream>>>(W_h, W_hf, W1_t, W23_t, Wf_t);
    gemm1_mfma<<<(N_NODES + 63) / 64, 256, 0, stream>>>(hidden, W1_t, rn_out, h1n);
    aggregate_kernel<<<(N_NODES + 3) / 4, 256, 0, stream>>>(
        (const unsigned*)h1n, row_start, col, rn_in, (unsigned*)conv_bf);
    final_mfma<<<(N_NODES + 63) / 64, 256, 0, stream>>>(hidden, conv_bf, W23_t, Wf_t, out);
}